// Round 2
// baseline (1701.341 us; speedup 1.0000x reference)
//
#include <hip/hip_runtime.h>
#include <math.h>

static constexpr int NB = 2, NN = 256, HH = 256, DD = 64, LL = 6;

typedef __attribute__((ext_vector_type(8))) short bf16x8;
typedef __attribute__((ext_vector_type(4))) float f32x4;
typedef __attribute__((ext_vector_type(4))) float float4v;

__device__ __forceinline__ float fsilu(float v) { return v / (1.0f + __expf(-v)); }

__device__ __forceinline__ unsigned short f2bf(float f) {
    union { float f; unsigned int u; } x; x.f = f;
    unsigned int r = x.u + 0x7fffu + ((x.u >> 16) & 1u);
    return (unsigned short)(r >> 16);
}
__device__ __forceinline__ float bf2f(unsigned short u) {
    union { float f; unsigned int u; } x; x.u = ((unsigned int)u) << 16; return x.f;
}

// ---------------------------------------------------------------- convert
// ew2T[l][col][k] = bf16(ew2[l][k][col]); same for cw1. k fastest.
__global__ void k_convert(const float* __restrict__ ew2, const float* __restrict__ cw1,
                          unsigned short* __restrict__ ew2T, unsigned short* __restrict__ cw1T) {
    int idx = blockIdx.x * blockDim.x + threadIdx.x;
    const int total = LL * HH * HH;
    if (idx >= total) return;
    int l = idx / (HH * HH);
    int rem = idx - l * (HH * HH);
    int col = rem >> 8;
    int k = rem & 255;
    ew2T[idx] = f2bf(ew2[(l * HH + k) * HH + col]);
    cw1T[idx] = f2bf(cw1[(l * HH + k) * HH + col]);
}

// ---------------------------------------------------------------- encoder (+time emb, x init)
__global__ __launch_bounds__(256) void k_encoder(
    const float* __restrict__ coords, const float* __restrict__ feats, const float* __restrict__ t,
    const float* __restrict__ pw1, const float* __restrict__ pb1,
    const float* __restrict__ pw2, const float* __restrict__ pb2,
    const float* __restrict__ pw3, const float* __restrict__ pb3,
    const float* __restrict__ tw1, const float* __restrict__ tb1,
    const float* __restrict__ tw2, const float* __restrict__ tb2,
    float* __restrict__ h, float* __restrict__ x) {
    __shared__ float spin[4][68];
    __shared__ float sha[4][HH];
    __shared__ float shb[4][HH];
    __shared__ float ste1[HH];
    int tid = threadIdx.x;
    int base = blockIdx.x * 4;
    int b = base / NN;

    for (int r = 0; r < 4; ++r) {
        int row = base + r;
        if (tid < 3) spin[r][tid] = coords[row * 3 + tid];
        if (tid < DD) spin[r][3 + tid] = feats[row * DD + tid];
    }
    float tv = t[b];
    ste1[tid] = fmaxf(tv * tw1[tid] + tb1[tid], 0.0f);
    if (tid < 12) {
        int r = tid / 3, c = tid % 3;
        x[(base + r) * 3 + c] = coords[(base + r) * 3 + c];
    }
    __syncthreads();

    float a0 = pb1[tid], a1 = a0, a2 = a0, a3 = a0;
    for (int c = 0; c < 67; ++c) {
        float w = pw1[c * HH + tid];
        a0 += spin[0][c] * w; a1 += spin[1][c] * w; a2 += spin[2][c] * w; a3 += spin[3][c] * w;
    }
    sha[0][tid] = fmaxf(a0, 0.f); sha[1][tid] = fmaxf(a1, 0.f);
    sha[2][tid] = fmaxf(a2, 0.f); sha[3][tid] = fmaxf(a3, 0.f);
    __syncthreads();
    a0 = pb2[tid]; a1 = a0; a2 = a0; a3 = a0;
    for (int c = 0; c < HH; ++c) {
        float w = pw2[c * HH + tid];
        a0 += sha[0][c] * w; a1 += sha[1][c] * w; a2 += sha[2][c] * w; a3 += sha[3][c] * w;
    }
    shb[0][tid] = fmaxf(a0, 0.f); shb[1][tid] = fmaxf(a1, 0.f);
    shb[2][tid] = fmaxf(a2, 0.f); shb[3][tid] = fmaxf(a3, 0.f);
    __syncthreads();
    a0 = pb3[tid]; a1 = a0; a2 = a0; a3 = a0;
    float te = tb2[tid];
    for (int c = 0; c < HH; ++c) {
        float w = pw3[c * HH + tid];
        a0 += shb[0][c] * w; a1 += shb[1][c] * w; a2 += shb[2][c] * w; a3 += shb[3][c] * w;
        te += ste1[c] * tw2[c * HH + tid];
    }
    h[(base + 0) * HH + tid] = fmaxf(a0, 0.f) + te;
    h[(base + 1) * HH + tid] = fmaxf(a1, 0.f) + te;
    h[(base + 2) * HH + tid] = fmaxf(a2, 0.f) + te;
    h[(base + 3) * HH + tid] = fmaxf(a3, 0.f) + te;
}

// ---------------------------------------------------------------- LayerNorm + Ai/Aj
// one wave per row (4 rows/block). Ai includes eb1 bias; Aj stored bf16.
__global__ __launch_bounds__(256) void k_ln_aiaj(
    const float* __restrict__ h, const float* __restrict__ g, const float* __restrict__ bta,
    const float* __restrict__ ew1l, const float* __restrict__ eb1l,
    float* __restrict__ hn, float* __restrict__ Ai, unsigned short* __restrict__ AjB) {
    __shared__ float shn[4][HH];
    int tid = threadIdx.x, w = tid >> 6, lane = tid & 63;
    int base = blockIdx.x * 4;
    int row = base + w;

    float v[4];
    #pragma unroll
    for (int q = 0; q < 4; ++q) v[q] = h[row * HH + lane + 64 * q];
    float s = v[0] + v[1] + v[2] + v[3];
    #pragma unroll
    for (int m = 1; m < 64; m <<= 1) s += __shfl_xor(s, m);
    float mu = s * (1.0f / HH);
    float var = 0.f;
    #pragma unroll
    for (int q = 0; q < 4; ++q) { v[q] -= mu; var += v[q] * v[q]; }
    #pragma unroll
    for (int m = 1; m < 64; m <<= 1) var += __shfl_xor(var, m);
    float rstd = rsqrtf(var * (1.0f / HH) + 1e-5f);
    #pragma unroll
    for (int q = 0; q < 4; ++q) {
        int k = lane + 64 * q;
        float hv = v[q] * rstd * g[k] + bta[k];
        shn[w][k] = hv;
        hn[row * HH + k] = hv;
    }
    __syncthreads();

    float ai0 = eb1l[tid], ai1 = ai0, ai2 = ai0, ai3 = ai0;
    float aj0 = 0.f, aj1 = 0.f, aj2 = 0.f, aj3 = 0.f;
    for (int c = 0; c < HH; ++c) {
        float wi = ew1l[c * HH + tid];
        float wj = ew1l[(HH + c) * HH + tid];
        float s0 = shn[0][c], s1 = shn[1][c], s2 = shn[2][c], s3 = shn[3][c];
        ai0 += s0 * wi; ai1 += s1 * wi; ai2 += s2 * wi; ai3 += s3 * wi;
        aj0 += s0 * wj; aj1 += s1 * wj; aj2 += s2 * wj; aj3 += s3 * wj;
    }
    Ai[(base + 0) * HH + tid] = ai0; AjB[(base + 0) * HH + tid] = f2bf(aj0);
    Ai[(base + 1) * HH + tid] = ai1; AjB[(base + 1) * HH + tid] = f2bf(aj1);
    Ai[(base + 2) * HH + tid] = ai2; AjB[(base + 2) * HH + tid] = f2bf(aj2);
    Ai[(base + 3) * HH + tid] = ai3; AjB[(base + 3) * HH + tid] = f2bf(aj3);
}

// ---------------------------------------------------------------- fused edge pipeline (MFMA)
// 512 threads = 8 waves; one block per (b,i). Each wave owns 32 output cols and
// holds its ew2/cw1 B-fragments in registers for the whole block (no global loads
// inside the MFMA loops). A-tiles (s, m) live in XOR-swizzled LDS.
__global__ __launch_bounds__(512, 2) void k_edge(
    const float* __restrict__ x, const float* __restrict__ Ai, const unsigned short* __restrict__ AjB,
    const float* __restrict__ wd, const float* __restrict__ eb2v,
    const unsigned short* __restrict__ ew2T, const unsigned short* __restrict__ cw1T,
    const float* __restrict__ cb1v, const float* __restrict__ cw2v, const float* __restrict__ cb2p,
    float* __restrict__ magg, float* __restrict__ xdelta) {
    __shared__ float srel[64][3];
    __shared__ float sd2[64];
    __shared__ float cwpart[8][64];
    __shared__ unsigned short s_tile[64 * 256];  // bf16, rows of 512B, XOR ((row&7)<<4)
    __shared__ unsigned short m_tile[64 * 256];

    int tid = threadIdx.x, wv = tid >> 6, lane = tid & 63;
    int g4 = lane >> 4, l15 = lane & 15;
    int colbase = wv * 32;
    int bi = blockIdx.x;
    int b = bi >> 8, i = bi & 255;
    int ni = b * NN + i;
    int bbase = b * NN;

    // ---- per-thread resident constants
    int k0p = (tid & 31) << 3;  // phase-1 k-slot (thread-invariant across iters)
    float aiv[8], wdv[8];
    {
        float4v a0 = *(const float4v*)(Ai + (size_t)ni * HH + k0p);
        float4v a1 = *(const float4v*)(Ai + (size_t)ni * HH + k0p + 4);
        float4v w0 = *(const float4v*)(wd + k0p);
        float4v w1 = *(const float4v*)(wd + k0p + 4);
        #pragma unroll
        for (int e = 0; e < 4; ++e) { aiv[e] = a0[e]; aiv[4 + e] = a1[e]; wdv[e] = w0[e]; wdv[4 + e] = w1[e]; }
    }
    float eb2r[2], cb1r[2], cw2r[2];
    #pragma unroll
    for (int ct = 0; ct < 2; ++ct) {
        int col = colbase + ct * 16 + l15;
        eb2r[ct] = eb2v[col]; cb1r[ct] = cb1v[col]; cw2r[ct] = cw2v[col];
    }
    float xi0 = x[ni * 3 + 0], xi1 = x[ni * 3 + 1], xi2 = x[ni * 3 + 2];
    float cb2 = cb2p[0];

    // ---- resident B fragments (64 + 64 VGPRs)
    bf16x8 Bew[8][2], Bcw[8][2];
    #pragma unroll
    for (int ks = 0; ks < 8; ++ks) {
        #pragma unroll
        for (int ct = 0; ct < 2; ++ct) {
            int col = colbase + ct * 16 + l15;
            int ak = ks * 32 + g4 * 8;
            Bew[ks][ct] = *(const bf16x8*)(ew2T + (size_t)col * HH + ak);
            Bcw[ks][ct] = *(const bf16x8*)(cw1T + (size_t)col * HH + ak);
        }
    }

    float mg[2] = {0.f, 0.f};
    float xd0 = 0.f, xd1 = 0.f, xd2 = 0.f;

    for (int jc = 0; jc < 4; ++jc) {
        int j0 = jc * 64;
        __syncthreads();  // prev iter's srel/cwpart consumers done
        if (tid < 64) {
            int j = bbase + j0 + tid;
            float rx = xi0 - x[j * 3 + 0];
            float ry = xi1 - x[j * 3 + 1];
            float rz = xi2 - x[j * 3 + 2];
            srel[tid][0] = rx; srel[tid][1] = ry; srel[tid][2] = rz;
            sd2[tid] = rx * rx + ry * ry + rz * rz;
        }
        __syncthreads();

        // ---- phase 1: s tile = silu(Ai + Aj + d2*wd), 64x256 bf16
        #pragma unroll
        for (int it = 0; it < 4; ++it) {
            int row = it * 16 + (tid >> 5);
            float d2v = sd2[row];
            bf16x8 ajv = *(const bf16x8*)(AjB + ((size_t)(bbase + j0 + row) * HH + k0p));
            bf16x8 sv;
            #pragma unroll
            for (int e = 0; e < 8; ++e) {
                float vy = aiv[e] + bf2f((unsigned short)ajv[e]) + d2v * wdv[e];
                sv[e] = (short)f2bf(fsilu(vy));
            }
            unsigned off = (unsigned)(row * 512 + k0p * 2) ^ (unsigned)((row & 7) << 4);
            *reinterpret_cast<bf16x8*>(reinterpret_cast<char*>(s_tile) + off) = sv;
        }
        __syncthreads();

        // ---- phase 2: m = silu(s @ ew2 + eb2)
        {
            f32x4 acc[4][2];
            #pragma unroll
            for (int rt = 0; rt < 4; ++rt)
                #pragma unroll
                for (int ct = 0; ct < 2; ++ct) acc[rt][ct] = (f32x4){0.f, 0.f, 0.f, 0.f};
            #pragma unroll
            for (int ks = 0; ks < 8; ++ks) {
                int ak = ks * 32 + g4 * 8;
                bf16x8 afr[4];
                #pragma unroll
                for (int rt = 0; rt < 4; ++rt) {
                    int row = rt * 16 + l15;
                    unsigned off = (unsigned)(row * 512 + ak * 2) ^ (unsigned)((row & 7) << 4);
                    afr[rt] = *reinterpret_cast<const bf16x8*>(reinterpret_cast<const char*>(s_tile) + off);
                }
                #pragma unroll
                for (int rt = 0; rt < 4; ++rt)
                    #pragma unroll
                    for (int ct = 0; ct < 2; ++ct)
                        acc[rt][ct] = __builtin_amdgcn_mfma_f32_16x16x32_bf16(afr[rt], Bew[ks][ct], acc[rt][ct], 0, 0, 0);
            }
            #pragma unroll
            for (int ct = 0; ct < 2; ++ct) {
                int col = colbase + ct * 16 + l15;
                #pragma unroll
                for (int rt = 0; rt < 4; ++rt) {
                    #pragma unroll
                    for (int r = 0; r < 4; ++r) {
                        int row = rt * 16 + g4 * 4 + r;
                        float vy = fsilu(acc[rt][ct][r] + eb2r[ct]);
                        mg[ct] += vy;
                        unsigned off = (unsigned)(row * 512 + col * 2) ^ (unsigned)((row & 7) << 4);
                        *reinterpret_cast<unsigned short*>(reinterpret_cast<char*>(m_tile) + off) = f2bf(vy);
                    }
                }
            }
        }
        __syncthreads();

        // ---- phase 3: c = silu(m @ cw1 + cb1); cw-row-dot with cw2
        {
            f32x4 acc[4][2];
            #pragma unroll
            for (int rt = 0; rt < 4; ++rt)
                #pragma unroll
                for (int ct = 0; ct < 2; ++ct) acc[rt][ct] = (f32x4){0.f, 0.f, 0.f, 0.f};
            #pragma unroll
            for (int ks = 0; ks < 8; ++ks) {
                int ak = ks * 32 + g4 * 8;
                bf16x8 afr[4];
                #pragma unroll
                for (int rt = 0; rt < 4; ++rt) {
                    int row = rt * 16 + l15;
                    unsigned off = (unsigned)(row * 512 + ak * 2) ^ (unsigned)((row & 7) << 4);
                    afr[rt] = *reinterpret_cast<const bf16x8*>(reinterpret_cast<const char*>(m_tile) + off);
                }
                #pragma unroll
                for (int rt = 0; rt < 4; ++rt)
                    #pragma unroll
                    for (int ct = 0; ct < 2; ++ct)
                        acc[rt][ct] = __builtin_amdgcn_mfma_f32_16x16x32_bf16(afr[rt], Bcw[ks][ct], acc[rt][ct], 0, 0, 0);
            }
            float rs[16];
            #pragma unroll
            for (int q = 0; q < 16; ++q) rs[q] = 0.f;
            #pragma unroll
            for (int ct = 0; ct < 2; ++ct) {
                #pragma unroll
                for (int rt = 0; rt < 4; ++rt)
                    #pragma unroll
                    for (int r = 0; r < 4; ++r)
                        rs[rt * 4 + r] += fsilu(acc[rt][ct][r] + cb1r[ct]) * cw2r[ct];
            }
            #pragma unroll
            for (int m = 1; m <= 8; m <<= 1)
                #pragma unroll
                for (int q = 0; q < 16; ++q) rs[q] += __shfl_xor(rs[q], m);
            if (l15 == 0) {
                int rb = g4 * 4;
                #pragma unroll
                for (int rt = 0; rt < 4; ++rt)
                    #pragma unroll
                    for (int r = 0; r < 4; ++r)
                        cwpart[wv][rt * 16 + rb + r] = rs[rt * 4 + r];
            }
        }
        __syncthreads();
        if (tid < 64) {
            float cwv = cb2;
            #pragma unroll
            for (int w = 0; w < 8; ++w) cwv += cwpart[w][tid];
            float p0 = srel[tid][0] * cwv;
            float p1 = srel[tid][1] * cwv;
            float p2 = srel[tid][2] * cwv;
            #pragma unroll
            for (int m = 1; m < 64; m <<= 1) {
                p0 += __shfl_xor(p0, m); p1 += __shfl_xor(p1, m); p2 += __shfl_xor(p2, m);
            }
            xd0 += p0; xd1 += p1; xd2 += p2;
        }
    }

    // magg: sum the 4 row-groups per col
    #pragma unroll
    for (int ct = 0; ct < 2; ++ct) {
        mg[ct] += __shfl_xor(mg[ct], 16);
        mg[ct] += __shfl_xor(mg[ct], 32);
    }
    if (lane < 16) {
        #pragma unroll
        for (int ct = 0; ct < 2; ++ct)
            magg[(size_t)ni * HH + colbase + ct * 16 + lane] = mg[ct];
    }
    if (tid == 0) {
        xdelta[ni * 3 + 0] = xd0 * (1.0f / NN);
        xdelta[ni * 3 + 1] = xd1 * (1.0f / NN);
        xdelta[ni * 3 + 2] = xd2 * (1.0f / NN);
    }
}

// ---------------------------------------------------------------- node update (+x update)
__global__ __launch_bounds__(256) void k_node(
    const float* __restrict__ hn, const float* __restrict__ magg,
    const float* __restrict__ nw1l, const float* __restrict__ nb1l,
    const float* __restrict__ nw2l, const float* __restrict__ nb2l,
    float* __restrict__ h, float* __restrict__ x, const float* __restrict__ xdelta) {
    __shared__ float s2[4][2 * HH];
    __shared__ float su[4][HH];
    int tid = threadIdx.x;
    int base = blockIdx.x * 4;
    for (int r = 0; r < 4; ++r) {
        s2[r][tid] = hn[(base + r) * HH + tid];
        s2[r][HH + tid] = magg[(base + r) * HH + tid];
    }
    if (tid < 12) {
        int r = tid / 3, c = tid % 3;
        x[(base + r) * 3 + c] += xdelta[(base + r) * 3 + c];
    }
    __syncthreads();
    float a0 = nb1l[tid], a1 = a0, a2 = a0, a3 = a0;
    for (int c = 0; c < 2 * HH; ++c) {
        float w = nw1l[c * HH + tid];
        a0 += s2[0][c] * w; a1 += s2[1][c] * w; a2 += s2[2][c] * w; a3 += s2[3][c] * w;
    }
    su[0][tid] = fsilu(a0); su[1][tid] = fsilu(a1); su[2][tid] = fsilu(a2); su[3][tid] = fsilu(a3);
    __syncthreads();
    float d0 = nb2l[tid], d1 = d0, d2 = d0, d3 = d0;
    for (int c = 0; c < HH; ++c) {
        float w = nw2l[c * HH + tid];
        d0 += su[0][c] * w; d1 += su[1][c] * w; d2 += su[2][c] * w; d3 += su[3][c] * w;
    }
    h[(base + 0) * HH + tid] += d0;
    h[(base + 1) * HH + tid] += d1;
    h[(base + 2) * HH + tid] += d2;
    h[(base + 3) * HH + tid] += d3;
}

// ---------------------------------------------------------------- decoder
__global__ __launch_bounds__(256) void k_decoder(
    const float* __restrict__ h,
    const float* __restrict__ dw1, const float* __restrict__ db1,
    const float* __restrict__ dw2, const float* __restrict__ db2,
    const float* __restrict__ dw3, const float* __restrict__ db3,
    float* __restrict__ out) {
    __shared__ float sh[4][HH];
    __shared__ float so1[4][HH];
    __shared__ float so2[4][HH];
    int tid = threadIdx.x;
    int base = blockIdx.x * 4;
    for (int r = 0; r < 4; ++r) sh[r][tid] = h[(base + r) * HH + tid];
    __syncthreads();
    float a0 = db1[tid], a1 = a0, a2 = a0, a3 = a0;
    for (int c = 0; c < HH; ++c) {
        float w = dw1[c * HH + tid];
        a0 += sh[0][c] * w; a1 += sh[1][c] * w; a2 += sh[2][c] * w; a3 += sh[3][c] * w;
    }
    so1[0][tid] = fmaxf(a0, 0.f); so1[1][tid] = fmaxf(a1, 0.f);
    so1[2][tid] = fmaxf(a2, 0.f); so1[3][tid] = fmaxf(a3, 0.f);
    __syncthreads();
    a0 = db2[tid]; a1 = a0; a2 = a0; a3 = a0;
    for (int c = 0; c < HH; ++c) {
        float w = dw2[c * HH + tid];
        a0 += so1[0][c] * w; a1 += so1[1][c] * w; a2 += so1[2][c] * w; a3 += so1[3][c] * w;
    }
    so2[0][tid] = fmaxf(a0, 0.f) + sh[0][tid];
    so2[1][tid] = fmaxf(a1, 0.f) + sh[1][tid];
    so2[2][tid] = fmaxf(a2, 0.f) + sh[2][tid];
    so2[3][tid] = fmaxf(a3, 0.f) + sh[3][tid];
    __syncthreads();
    if (tid < 12) {
        int r = tid / 3, c = tid % 3;
        float acc = db3[c];
        for (int k = 0; k < HH; ++k) acc += so2[r][k] * dw3[k * 3 + c];
        out[(base + r) * 3 + c] = acc;
    }
}

// ---------------------------------------------------------------- launch
extern "C" void kernel_launch(void* const* d_in, const int* in_sizes, int n_in,
                              void* d_out, int out_size, void* d_ws, size_t ws_size,
                              hipStream_t stream) {
    const float* coords = (const float*)d_in[0];
    const float* feats  = (const float*)d_in[1];
    const float* t      = (const float*)d_in[2];
    const float* pe_w1  = (const float*)d_in[3];  const float* pe_b1 = (const float*)d_in[4];
    const float* pe_w2  = (const float*)d_in[5];  const float* pe_b2 = (const float*)d_in[6];
    const float* pe_w3  = (const float*)d_in[7];  const float* pe_b3 = (const float*)d_in[8];
    const float* te_w1  = (const float*)d_in[9];  const float* te_b1 = (const float*)d_in[10];
    const float* te_w2  = (const float*)d_in[11]; const float* te_b2 = (const float*)d_in[12];
    const float* ln_g   = (const float*)d_in[13]; const float* ln_b  = (const float*)d_in[14];
    const float* ew1    = (const float*)d_in[15]; const float* eb1   = (const float*)d_in[16];
    const float* ew2    = (const float*)d_in[17]; const float* eb2   = (const float*)d_in[18];
    const float* cw1    = (const float*)d_in[19]; const float* cb1   = (const float*)d_in[20];
    const float* cw2    = (const float*)d_in[21]; const float* cb2   = (const float*)d_in[22];
    const float* nw1    = (const float*)d_in[23]; const float* nb1   = (const float*)d_in[24];
    const float* nw2    = (const float*)d_in[25]; const float* nb2   = (const float*)d_in[26];
    const float* dec_w1 = (const float*)d_in[27]; const float* dec_b1 = (const float*)d_in[28];
    const float* dec_w2 = (const float*)d_in[29]; const float* dec_b2 = (const float*)d_in[30];
    const float* dec_w3 = (const float*)d_in[31]; const float* dec_b3 = (const float*)d_in[32];

    float* ws = (float*)d_ws;
    const int RN = NB * NN * HH;  // 131072
    float* h      = ws;
    float* hn     = ws + RN;
    float* Ai     = ws + 2 * RN;
    float* magg   = ws + 3 * RN;
    float* x      = ws + 4 * RN;            // 1536 (reserve 2048)
    float* xdelta = ws + 4 * RN + 2048;     // 1536 (reserve 2048)
    unsigned short* AjB  = (unsigned short*)(ws + 4 * RN + 4096);
    unsigned short* ew2T = AjB + RN;
    unsigned short* cw1T = ew2T + LL * HH * HH;
    // ~2 MB f32 + ~1.8 MB bf16 of d_ws

    k_convert<<<(LL * HH * HH + 511) / 512, 512, 0, stream>>>(ew2, cw1, ew2T, cw1T);
    k_encoder<<<NB * NN / 4, 256, 0, stream>>>(coords, feats, t,
        pe_w1, pe_b1, pe_w2, pe_b2, pe_w3, pe_b3, te_w1, te_b1, te_w2, te_b2, h, x);

    for (int l = 0; l < LL; ++l) {
        k_ln_aiaj<<<NB * NN / 4, 256, 0, stream>>>(h, ln_g + l * HH, ln_b + l * HH,
            ew1 + (size_t)l * 513 * HH, eb1 + l * HH, hn, Ai, AjB);
        k_edge<<<NB * NN, 512, 0, stream>>>(x, Ai, AjB,
            ew1 + ((size_t)l * 513 + 512) * HH, eb2 + l * HH,
            ew2T + (size_t)l * HH * HH, cw1T + (size_t)l * HH * HH,
            cb1 + l * HH, cw2 + l * HH, cb2 + l, magg, xdelta);
        k_node<<<NB * NN / 4, 256, 0, stream>>>(hn, magg,
            nw1 + (size_t)l * 2 * HH * HH, nb1 + l * HH,
            nw2 + (size_t)l * HH * HH, nb2 + l * HH, h, x, xdelta);
    }

    k_decoder<<<NB * NN / 4, 256, 0, stream>>>(h, dec_w1, dec_b1, dec_w2, dec_b2,
                                               dec_w3, dec_b3, (float*)d_out);
}

// Round 3
// 1664.353 us; speedup vs baseline: 1.0222x; 1.0222x over previous
//
#include <hip/hip_runtime.h>
#include <math.h>

static constexpr int NB = 2, NN = 256, HH = 256, DD = 64, LL = 6;

typedef __attribute__((ext_vector_type(8))) short bf16x8;
typedef __attribute__((ext_vector_type(4))) float f32x4;
typedef __attribute__((ext_vector_type(4))) float float4v;

__device__ __forceinline__ float fsilu(float v) { return v / (1.0f + __expf(-v)); }

__device__ __forceinline__ unsigned short f2bf(float f) {
    union { float f; unsigned int u; } x; x.f = f;
    unsigned int r = x.u + 0x7fffu + ((x.u >> 16) & 1u);
    return (unsigned short)(r >> 16);
}
__device__ __forceinline__ float bf2f(unsigned short u) {
    union { float f; unsigned int u; } x; x.u = ((unsigned int)u) << 16; return x.f;
}

// ---------------------------------------------------------------- convert
// ew2T[l][col][k] = bf16(ew2[l][k][col]); same for cw1. k fastest.
__global__ void k_convert(const float* __restrict__ ew2, const float* __restrict__ cw1,
                          unsigned short* __restrict__ ew2T, unsigned short* __restrict__ cw1T) {
    int idx = blockIdx.x * blockDim.x + threadIdx.x;
    const int total = LL * HH * HH;
    if (idx >= total) return;
    int l = idx / (HH * HH);
    int rem = idx - l * (HH * HH);
    int col = rem >> 8;
    int k = rem & 255;
    ew2T[idx] = f2bf(ew2[(l * HH + k) * HH + col]);
    cw1T[idx] = f2bf(cw1[(l * HH + k) * HH + col]);
}

// ---------------------------------------------------------------- encoder (+time emb, x init)
__global__ __launch_bounds__(256) void k_encoder(
    const float* __restrict__ coords, const float* __restrict__ feats, const float* __restrict__ t,
    const float* __restrict__ pw1, const float* __restrict__ pb1,
    const float* __restrict__ pw2, const float* __restrict__ pb2,
    const float* __restrict__ pw3, const float* __restrict__ pb3,
    const float* __restrict__ tw1, const float* __restrict__ tb1,
    const float* __restrict__ tw2, const float* __restrict__ tb2,
    float* __restrict__ h, float* __restrict__ x) {
    __shared__ float spin[4][68];
    __shared__ float sha[4][HH];
    __shared__ float shb[4][HH];
    __shared__ float ste1[HH];
    int tid = threadIdx.x;
    int base = blockIdx.x * 4;
    int b = base / NN;

    for (int r = 0; r < 4; ++r) {
        int row = base + r;
        if (tid < 3) spin[r][tid] = coords[row * 3 + tid];
        if (tid < DD) spin[r][3 + tid] = feats[row * DD + tid];
    }
    float tv = t[b];
    ste1[tid] = fmaxf(tv * tw1[tid] + tb1[tid], 0.0f);
    if (tid < 12) {
        int r = tid / 3, c = tid % 3;
        x[(base + r) * 3 + c] = coords[(base + r) * 3 + c];
    }
    __syncthreads();

    float a0 = pb1[tid], a1 = a0, a2 = a0, a3 = a0;
    for (int c = 0; c < 67; ++c) {
        float w = pw1[c * HH + tid];
        a0 += spin[0][c] * w; a1 += spin[1][c] * w; a2 += spin[2][c] * w; a3 += spin[3][c] * w;
    }
    sha[0][tid] = fmaxf(a0, 0.f); sha[1][tid] = fmaxf(a1, 0.f);
    sha[2][tid] = fmaxf(a2, 0.f); sha[3][tid] = fmaxf(a3, 0.f);
    __syncthreads();
    a0 = pb2[tid]; a1 = a0; a2 = a0; a3 = a0;
    for (int c = 0; c < HH; ++c) {
        float w = pw2[c * HH + tid];
        a0 += sha[0][c] * w; a1 += sha[1][c] * w; a2 += sha[2][c] * w; a3 += sha[3][c] * w;
    }
    shb[0][tid] = fmaxf(a0, 0.f); shb[1][tid] = fmaxf(a1, 0.f);
    shb[2][tid] = fmaxf(a2, 0.f); shb[3][tid] = fmaxf(a3, 0.f);
    __syncthreads();
    a0 = pb3[tid]; a1 = a0; a2 = a0; a3 = a0;
    float te = tb2[tid];
    for (int c = 0; c < HH; ++c) {
        float w = pw3[c * HH + tid];
        a0 += shb[0][c] * w; a1 += shb[1][c] * w; a2 += shb[2][c] * w; a3 += shb[3][c] * w;
        te += ste1[c] * tw2[c * HH + tid];
    }
    h[(base + 0) * HH + tid] = fmaxf(a0, 0.f) + te;
    h[(base + 1) * HH + tid] = fmaxf(a1, 0.f) + te;
    h[(base + 2) * HH + tid] = fmaxf(a2, 0.f) + te;
    h[(base + 3) * HH + tid] = fmaxf(a3, 0.f) + te;
}

// ---------------------------------------------------------------- LayerNorm + Ai/Aj
// one wave per row (4 rows/block). Ai includes eb1 bias; Aj stored bf16.
__global__ __launch_bounds__(256) void k_ln_aiaj(
    const float* __restrict__ h, const float* __restrict__ g, const float* __restrict__ bta,
    const float* __restrict__ ew1l, const float* __restrict__ eb1l,
    float* __restrict__ hn, float* __restrict__ Ai, unsigned short* __restrict__ AjB) {
    __shared__ float shn[4][HH];
    int tid = threadIdx.x, w = tid >> 6, lane = tid & 63;
    int base = blockIdx.x * 4;
    int row = base + w;

    float v[4];
    #pragma unroll
    for (int q = 0; q < 4; ++q) v[q] = h[row * HH + lane + 64 * q];
    float s = v[0] + v[1] + v[2] + v[3];
    #pragma unroll
    for (int m = 1; m < 64; m <<= 1) s += __shfl_xor(s, m);
    float mu = s * (1.0f / HH);
    float var = 0.f;
    #pragma unroll
    for (int q = 0; q < 4; ++q) { v[q] -= mu; var += v[q] * v[q]; }
    #pragma unroll
    for (int m = 1; m < 64; m <<= 1) var += __shfl_xor(var, m);
    float rstd = rsqrtf(var * (1.0f / HH) + 1e-5f);
    #pragma unroll
    for (int q = 0; q < 4; ++q) {
        int k = lane + 64 * q;
        float hv = v[q] * rstd * g[k] + bta[k];
        shn[w][k] = hv;
        hn[row * HH + k] = hv;
    }
    __syncthreads();

    float ai0 = eb1l[tid], ai1 = ai0, ai2 = ai0, ai3 = ai0;
    float aj0 = 0.f, aj1 = 0.f, aj2 = 0.f, aj3 = 0.f;
    for (int c = 0; c < HH; ++c) {
        float wi = ew1l[c * HH + tid];
        float wj = ew1l[(HH + c) * HH + tid];
        float s0 = shn[0][c], s1 = shn[1][c], s2 = shn[2][c], s3 = shn[3][c];
        ai0 += s0 * wi; ai1 += s1 * wi; ai2 += s2 * wi; ai3 += s3 * wi;
        aj0 += s0 * wj; aj1 += s1 * wj; aj2 += s2 * wj; aj3 += s3 * wj;
    }
    Ai[(base + 0) * HH + tid] = ai0; AjB[(base + 0) * HH + tid] = f2bf(aj0);
    Ai[(base + 1) * HH + tid] = ai1; AjB[(base + 1) * HH + tid] = f2bf(aj1);
    Ai[(base + 2) * HH + tid] = ai2; AjB[(base + 2) * HH + tid] = f2bf(aj2);
    Ai[(base + 3) * HH + tid] = ai3; AjB[(base + 3) * HH + tid] = f2bf(aj3);
}

// ---------------------------------------------------------------- fused edge pipeline (MFMA)
// 512 threads = 8 waves; one block per (b,i). Each wave owns 32 output cols and
// holds its ew2/cw1 B-fragments in registers for the whole block.
// amdgpu_waves_per_eu(2,2): pin regalloc target at 2 waves/SIMD -> 256-VGPR
// budget so the ~217-reg working set does NOT spill (round-2 failure mode:
// 128-reg cap -> 110 MB of scratch stores per dispatch).
__global__ __launch_bounds__(512) __attribute__((amdgpu_waves_per_eu(2, 2))) void k_edge(
    const float* __restrict__ x, const float* __restrict__ Ai, const unsigned short* __restrict__ AjB,
    const float* __restrict__ wd, const float* __restrict__ eb2v,
    const unsigned short* __restrict__ ew2T, const unsigned short* __restrict__ cw1T,
    const float* __restrict__ cb1v, const float* __restrict__ cw2v, const float* __restrict__ cb2p,
    float* __restrict__ magg, float* __restrict__ xdelta) {
    __shared__ float srel[64][3];
    __shared__ float sd2[64];
    __shared__ float cwpart[8][64];
    __shared__ unsigned short s_tile[64 * 256];  // bf16, rows of 512B, XOR ((row&7)<<4)
    __shared__ unsigned short m_tile[64 * 256];

    int tid = threadIdx.x, wv = tid >> 6, lane = tid & 63;
    int g4 = lane >> 4, l15 = lane & 15;
    int colbase = wv * 32;
    int bi = blockIdx.x;
    int b = bi >> 8, i = bi & 255;
    int ni = b * NN + i;
    int bbase = b * NN;

    // ---- per-thread resident constants
    int k0p = (tid & 31) << 3;  // phase-1 k-slot (thread-invariant across iters)
    float aiv[8], wdv[8];
    {
        float4v a0 = *(const float4v*)(Ai + (size_t)ni * HH + k0p);
        float4v a1 = *(const float4v*)(Ai + (size_t)ni * HH + k0p + 4);
        float4v w0 = *(const float4v*)(wd + k0p);
        float4v w1 = *(const float4v*)(wd + k0p + 4);
        #pragma unroll
        for (int e = 0; e < 4; ++e) { aiv[e] = a0[e]; aiv[4 + e] = a1[e]; wdv[e] = w0[e]; wdv[4 + e] = w1[e]; }
    }
    float eb2r[2], cb1r[2], cw2r[2];
    #pragma unroll
    for (int ct = 0; ct < 2; ++ct) {
        int col = colbase + ct * 16 + l15;
        eb2r[ct] = eb2v[col]; cb1r[ct] = cb1v[col]; cw2r[ct] = cw2v[col];
    }
    float xi0 = x[ni * 3 + 0], xi1 = x[ni * 3 + 1], xi2 = x[ni * 3 + 2];
    float cb2 = cb2p[0];

    // ---- resident B fragments (64 + 64 VGPRs)
    bf16x8 Bew[8][2], Bcw[8][2];
    #pragma unroll
    for (int ks = 0; ks < 8; ++ks) {
        #pragma unroll
        for (int ct = 0; ct < 2; ++ct) {
            int col = colbase + ct * 16 + l15;
            int ak = ks * 32 + g4 * 8;
            Bew[ks][ct] = *(const bf16x8*)(ew2T + (size_t)col * HH + ak);
            Bcw[ks][ct] = *(const bf16x8*)(cw1T + (size_t)col * HH + ak);
        }
    }

    float mg[2] = {0.f, 0.f};
    float xd0 = 0.f, xd1 = 0.f, xd2 = 0.f;

    for (int jc = 0; jc < 4; ++jc) {
        int j0 = jc * 64;
        __syncthreads();  // prev iter's srel/cwpart consumers done
        if (tid < 64) {
            int j = bbase + j0 + tid;
            float rx = xi0 - x[j * 3 + 0];
            float ry = xi1 - x[j * 3 + 1];
            float rz = xi2 - x[j * 3 + 2];
            srel[tid][0] = rx; srel[tid][1] = ry; srel[tid][2] = rz;
            sd2[tid] = rx * rx + ry * ry + rz * rz;
        }
        __syncthreads();

        // ---- phase 1: s tile = silu(Ai + Aj + d2*wd), 64x256 bf16
        #pragma unroll
        for (int it = 0; it < 4; ++it) {
            int row = it * 16 + (tid >> 5);
            float d2v = sd2[row];
            bf16x8 ajv = *(const bf16x8*)(AjB + ((size_t)(bbase + j0 + row) * HH + k0p));
            bf16x8 sv;
            #pragma unroll
            for (int e = 0; e < 8; ++e) {
                float vy = aiv[e] + bf2f((unsigned short)ajv[e]) + d2v * wdv[e];
                sv[e] = (short)f2bf(fsilu(vy));
            }
            unsigned off = (unsigned)(row * 512 + k0p * 2) ^ (unsigned)((row & 7) << 4);
            *reinterpret_cast<bf16x8*>(reinterpret_cast<char*>(s_tile) + off) = sv;
        }
        __syncthreads();

        // ---- phase 2: m = silu(s @ ew2 + eb2)
        {
            f32x4 acc[4][2];
            #pragma unroll
            for (int rt = 0; rt < 4; ++rt)
                #pragma unroll
                for (int ct = 0; ct < 2; ++ct) acc[rt][ct] = (f32x4){0.f, 0.f, 0.f, 0.f};
            #pragma unroll
            for (int ks = 0; ks < 8; ++ks) {
                int ak = ks * 32 + g4 * 8;
                bf16x8 afr[4];
                #pragma unroll
                for (int rt = 0; rt < 4; ++rt) {
                    int row = rt * 16 + l15;
                    unsigned off = (unsigned)(row * 512 + ak * 2) ^ (unsigned)((row & 7) << 4);
                    afr[rt] = *reinterpret_cast<const bf16x8*>(reinterpret_cast<const char*>(s_tile) + off);
                }
                #pragma unroll
                for (int rt = 0; rt < 4; ++rt)
                    #pragma unroll
                    for (int ct = 0; ct < 2; ++ct)
                        acc[rt][ct] = __builtin_amdgcn_mfma_f32_16x16x32_bf16(afr[rt], Bew[ks][ct], acc[rt][ct], 0, 0, 0);
            }
            #pragma unroll
            for (int ct = 0; ct < 2; ++ct) {
                int col = colbase + ct * 16 + l15;
                #pragma unroll
                for (int rt = 0; rt < 4; ++rt) {
                    #pragma unroll
                    for (int r = 0; r < 4; ++r) {
                        int row = rt * 16 + g4 * 4 + r;
                        float vy = fsilu(acc[rt][ct][r] + eb2r[ct]);
                        mg[ct] += vy;
                        unsigned off = (unsigned)(row * 512 + col * 2) ^ (unsigned)((row & 7) << 4);
                        *reinterpret_cast<unsigned short*>(reinterpret_cast<char*>(m_tile) + off) = f2bf(vy);
                    }
                }
            }
        }
        __syncthreads();

        // ---- phase 3: c = silu(m @ cw1 + cb1); cw-row-dot with cw2
        {
            f32x4 acc[4][2];
            #pragma unroll
            for (int rt = 0; rt < 4; ++rt)
                #pragma unroll
                for (int ct = 0; ct < 2; ++ct) acc[rt][ct] = (f32x4){0.f, 0.f, 0.f, 0.f};
            #pragma unroll
            for (int ks = 0; ks < 8; ++ks) {
                int ak = ks * 32 + g4 * 8;
                bf16x8 afr[4];
                #pragma unroll
                for (int rt = 0; rt < 4; ++rt) {
                    int row = rt * 16 + l15;
                    unsigned off = (unsigned)(row * 512 + ak * 2) ^ (unsigned)((row & 7) << 4);
                    afr[rt] = *reinterpret_cast<const bf16x8*>(reinterpret_cast<const char*>(m_tile) + off);
                }
                #pragma unroll
                for (int rt = 0; rt < 4; ++rt)
                    #pragma unroll
                    for (int ct = 0; ct < 2; ++ct)
                        acc[rt][ct] = __builtin_amdgcn_mfma_f32_16x16x32_bf16(afr[rt], Bcw[ks][ct], acc[rt][ct], 0, 0, 0);
            }
            float rs[16];
            #pragma unroll
            for (int q = 0; q < 16; ++q) rs[q] = 0.f;
            #pragma unroll
            for (int ct = 0; ct < 2; ++ct) {
                #pragma unroll
                for (int rt = 0; rt < 4; ++rt)
                    #pragma unroll
                    for (int r = 0; r < 4; ++r)
                        rs[rt * 4 + r] += fsilu(acc[rt][ct][r] + cb1r[ct]) * cw2r[ct];
            }
            #pragma unroll
            for (int m = 1; m <= 8; m <<= 1)
                #pragma unroll
                for (int q = 0; q < 16; ++q) rs[q] += __shfl_xor(rs[q], m);
            if (l15 == 0) {
                int rb = g4 * 4;
                #pragma unroll
                for (int rt = 0; rt < 4; ++rt)
                    #pragma unroll
                    for (int r = 0; r < 4; ++r)
                        cwpart[wv][rt * 16 + rb + r] = rs[rt * 4 + r];
            }
        }
        __syncthreads();
        if (tid < 64) {
            float cwv = cb2;
            #pragma unroll
            for (int w = 0; w < 8; ++w) cwv += cwpart[w][tid];
            float p0 = srel[tid][0] * cwv;
            float p1 = srel[tid][1] * cwv;
            float p2 = srel[tid][2] * cwv;
            #pragma unroll
            for (int m = 1; m < 64; m <<= 1) {
                p0 += __shfl_xor(p0, m); p1 += __shfl_xor(p1, m); p2 += __shfl_xor(p2, m);
            }
            xd0 += p0; xd1 += p1; xd2 += p2;
        }
    }

    // magg: sum the 4 row-groups per col
    #pragma unroll
    for (int ct = 0; ct < 2; ++ct) {
        mg[ct] += __shfl_xor(mg[ct], 16);
        mg[ct] += __shfl_xor(mg[ct], 32);
    }
    if (lane < 16) {
        #pragma unroll
        for (int ct = 0; ct < 2; ++ct)
            magg[(size_t)ni * HH + colbase + ct * 16 + lane] = mg[ct];
    }
    if (tid == 0) {
        xdelta[ni * 3 + 0] = xd0 * (1.0f / NN);
        xdelta[ni * 3 + 1] = xd1 * (1.0f / NN);
        xdelta[ni * 3 + 2] = xd2 * (1.0f / NN);
    }
}

// ---------------------------------------------------------------- node update (+x update)
__global__ __launch_bounds__(256) void k_node(
    const float* __restrict__ hn, const float* __restrict__ magg,
    const float* __restrict__ nw1l, const float* __restrict__ nb1l,
    const float* __restrict__ nw2l, const float* __restrict__ nb2l,
    float* __restrict__ h, float* __restrict__ x, const float* __restrict__ xdelta) {
    __shared__ float s2[4][2 * HH];
    __shared__ float su[4][HH];
    int tid = threadIdx.x;
    int base = blockIdx.x * 4;
    for (int r = 0; r < 4; ++r) {
        s2[r][tid] = hn[(base + r) * HH + tid];
        s2[r][HH + tid] = magg[(base + r) * HH + tid];
    }
    if (tid < 12) {
        int r = tid / 3, c = tid % 3;
        x[(base + r) * 3 + c] += xdelta[(base + r) * 3 + c];
    }
    __syncthreads();
    float a0 = nb1l[tid], a1 = a0, a2 = a0, a3 = a0;
    for (int c = 0; c < 2 * HH; ++c) {
        float w = nw1l[c * HH + tid];
        a0 += s2[0][c] * w; a1 += s2[1][c] * w; a2 += s2[2][c] * w; a3 += s2[3][c] * w;
    }
    su[0][tid] = fsilu(a0); su[1][tid] = fsilu(a1); su[2][tid] = fsilu(a2); su[3][tid] = fsilu(a3);
    __syncthreads();
    float d0 = nb2l[tid], d1 = d0, d2 = d0, d3 = d0;
    for (int c = 0; c < HH; ++c) {
        float w = nw2l[c * HH + tid];
        d0 += su[0][c] * w; d1 += su[1][c] * w; d2 += su[2][c] * w; d3 += su[3][c] * w;
    }
    h[(base + 0) * HH + tid] += d0;
    h[(base + 1) * HH + tid] += d1;
    h[(base + 2) * HH + tid] += d2;
    h[(base + 3) * HH + tid] += d3;
}

// ---------------------------------------------------------------- decoder
__global__ __launch_bounds__(256) void k_decoder(
    const float* __restrict__ h,
    const float* __restrict__ dw1, const float* __restrict__ db1,
    const float* __restrict__ dw2, const float* __restrict__ db2,
    const float* __restrict__ dw3, const float* __restrict__ db3,
    float* __restrict__ out) {
    __shared__ float sh[4][HH];
    __shared__ float so1[4][HH];
    __shared__ float so2[4][HH];
    int tid = threadIdx.x;
    int base = blockIdx.x * 4;
    for (int r = 0; r < 4; ++r) sh[r][tid] = h[(base + r) * HH + tid];
    __syncthreads();
    float a0 = db1[tid], a1 = a0, a2 = a0, a3 = a0;
    for (int c = 0; c < HH; ++c) {
        float w = dw1[c * HH + tid];
        a0 += sh[0][c] * w; a1 += sh[1][c] * w; a2 += sh[2][c] * w; a3 += sh[3][c] * w;
    }
    so1[0][tid] = fmaxf(a0, 0.f); so1[1][tid] = fmaxf(a1, 0.f);
    so1[2][tid] = fmaxf(a2, 0.f); so1[3][tid] = fmaxf(a3, 0.f);
    __syncthreads();
    a0 = db2[tid]; a1 = a0; a2 = a0; a3 = a0;
    for (int c = 0; c < HH; ++c) {
        float w = dw2[c * HH + tid];
        a0 += so1[0][c] * w; a1 += so1[1][c] * w; a2 += so1[2][c] * w; a3 += so1[3][c] * w;
    }
    so2[0][tid] = fmaxf(a0, 0.f) + sh[0][tid];
    so2[1][tid] = fmaxf(a1, 0.f) + sh[1][tid];
    so2[2][tid] = fmaxf(a2, 0.f) + sh[2][tid];
    so2[3][tid] = fmaxf(a3, 0.f) + sh[3][tid];
    __syncthreads();
    if (tid < 12) {
        int r = tid / 3, c = tid % 3;
        float acc = db3[c];
        for (int k = 0; k < HH; ++k) acc += so2[r][k] * dw3[k * 3 + c];
        out[(base + r) * 3 + c] = acc;
    }
}

// ---------------------------------------------------------------- launch
extern "C" void kernel_launch(void* const* d_in, const int* in_sizes, int n_in,
                              void* d_out, int out_size, void* d_ws, size_t ws_size,
                              hipStream_t stream) {
    const float* coords = (const float*)d_in[0];
    const float* feats  = (const float*)d_in[1];
    const float* t      = (const float*)d_in[2];
    const float* pe_w1  = (const float*)d_in[3];  const float* pe_b1 = (const float*)d_in[4];
    const float* pe_w2  = (const float*)d_in[5];  const float* pe_b2 = (const float*)d_in[6];
    const float* pe_w3  = (const float*)d_in[7];  const float* pe_b3 = (const float*)d_in[8];
    const float* te_w1  = (const float*)d_in[9];  const float* te_b1 = (const float*)d_in[10];
    const float* te_w2  = (const float*)d_in[11]; const float* te_b2 = (const float*)d_in[12];
    const float* ln_g   = (const float*)d_in[13]; const float* ln_b  = (const float*)d_in[14];
    const float* ew1    = (const float*)d_in[15]; const float* eb1   = (const float*)d_in[16];
    const float* ew2    = (const float*)d_in[17]; const float* eb2   = (const float*)d_in[18];
    const float* cw1    = (const float*)d_in[19]; const float* cb1   = (const float*)d_in[20];
    const float* cw2    = (const float*)d_in[21]; const float* cb2   = (const float*)d_in[22];
    const float* nw1    = (const float*)d_in[23]; const float* nb1   = (const float*)d_in[24];
    const float* nw2    = (const float*)d_in[25]; const float* nb2   = (const float*)d_in[26];
    const float* dec_w1 = (const float*)d_in[27]; const float* dec_b1 = (const float*)d_in[28];
    const float* dec_w2 = (const float*)d_in[29]; const float* dec_b2 = (const float*)d_in[30];
    const float* dec_w3 = (const float*)d_in[31]; const float* dec_b3 = (const float*)d_in[32];

    float* ws = (float*)d_ws;
    const int RN = NB * NN * HH;  // 131072
    float* h      = ws;
    float* hn     = ws + RN;
    float* Ai     = ws + 2 * RN;
    float* magg   = ws + 3 * RN;
    float* x      = ws + 4 * RN;            // 1536 (reserve 2048)
    float* xdelta = ws + 4 * RN + 2048;     // 1536 (reserve 2048)
    unsigned short* AjB  = (unsigned short*)(ws + 4 * RN + 4096);
    unsigned short* ew2T = AjB + RN;
    unsigned short* cw1T = ew2T + LL * HH * HH;
    // ~2 MB f32 + ~1.8 MB bf16 of d_ws

    k_convert<<<(LL * HH * HH + 511) / 512, 512, 0, stream>>>(ew2, cw1, ew2T, cw1T);
    k_encoder<<<NB * NN / 4, 256, 0, stream>>>(coords, feats, t,
        pe_w1, pe_b1, pe_w2, pe_b2, pe_w3, pe_b3, te_w1, te_b1, te_w2, te_b2, h, x);

    for (int l = 0; l < LL; ++l) {
        k_ln_aiaj<<<NB * NN / 4, 256, 0, stream>>>(h, ln_g + l * HH, ln_b + l * HH,
            ew1 + (size_t)l * 513 * HH, eb1 + l * HH, hn, Ai, AjB);
        k_edge<<<NB * NN, 512, 0, stream>>>(x, Ai, AjB,
            ew1 + ((size_t)l * 513 + 512) * HH, eb2 + l * HH,
            ew2T + (size_t)l * HH * HH, cw1T + (size_t)l * HH * HH,
            cb1 + l * HH, cw2 + l * HH, cb2 + l, magg, xdelta);
        k_node<<<NB * NN / 4, 256, 0, stream>>>(hn, magg,
            nw1 + (size_t)l * 2 * HH * HH, nb1 + l * HH,
            nw2 + (size_t)l * HH * HH, nb2 + l * HH, h, x, xdelta);
    }

    k_decoder<<<NB * NN / 4, 256, 0, stream>>>(h, dec_w1, dec_b1, dec_w2, dec_b2,
                                               dec_w3, dec_b3, (float*)d_out);
}

// Round 4
// 1631.634 us; speedup vs baseline: 1.0427x; 1.0201x over previous
//
#include <hip/hip_runtime.h>
#include <math.h>

static constexpr int NB = 2, NN = 256, HH = 256, DD = 64, LL = 6;

typedef __attribute__((ext_vector_type(8))) short bf16x8;
typedef __attribute__((ext_vector_type(4))) float f32x4;
typedef __attribute__((ext_vector_type(4))) float float4v;

__device__ __forceinline__ float fsilu(float v) { return v / (1.0f + __expf(-v)); }

__device__ __forceinline__ unsigned short f2bf(float f) {
    union { float f; unsigned int u; } x; x.f = f;
    unsigned int r = x.u + 0x7fffu + ((x.u >> 16) & 1u);
    return (unsigned short)(r >> 16);
}
__device__ __forceinline__ float bf2f(unsigned short u) {
    union { float f; unsigned int u; } x; x.u = ((unsigned int)u) << 16; return x.f;
}

// ---------------------------------------------------------------- convert (fragment-packed)
// Pack ew2/cw1 into the exact per-lane MFMA B-fragment stream so k_edge's B loads
// are fully coalesced:  elem[((l*8192 + (ks*16 + wv*2 + ct)*64 + lane)*8 + e]
//   = bf16( W[l][ k= ks*32+(lane>>4)*8+e ][ col= wv*32+ct*16+(lane&15) ] )
__global__ void k_convert(const float* __restrict__ ew2, const float* __restrict__ cw1,
                          unsigned short* __restrict__ ew2P, unsigned short* __restrict__ cw1P) {
    int g = blockIdx.x * blockDim.x + threadIdx.x;
    if (g >= LL * 8192) return;
    int l = g >> 13;
    int r = g & 8191;
    int lane = r & 63;
    int fidx = r >> 6;           // ks*16 + wv*2 + ct
    int ks = fidx >> 4;
    int wv = (fidx >> 1) & 7;
    int ct = fidx & 1;
    int col = wv * 32 + ct * 16 + (lane & 15);
    int k0 = ks * 32 + (lane >> 4) * 8;
    #pragma unroll
    for (int e = 0; e < 8; ++e) {
        ew2P[(size_t)g * 8 + e] = f2bf(ew2[((size_t)l * HH + k0 + e) * HH + col]);
        cw1P[(size_t)g * 8 + e] = f2bf(cw1[((size_t)l * HH + k0 + e) * HH + col]);
    }
}

// ---------------------------------------------------------------- encoder (+time emb, x init)
__global__ __launch_bounds__(256) void k_encoder(
    const float* __restrict__ coords, const float* __restrict__ feats, const float* __restrict__ t,
    const float* __restrict__ pw1, const float* __restrict__ pb1,
    const float* __restrict__ pw2, const float* __restrict__ pb2,
    const float* __restrict__ pw3, const float* __restrict__ pb3,
    const float* __restrict__ tw1, const float* __restrict__ tb1,
    const float* __restrict__ tw2, const float* __restrict__ tb2,
    float* __restrict__ h, float* __restrict__ x) {
    __shared__ float spin[4][68];
    __shared__ float sha[4][HH];
    __shared__ float shb[4][HH];
    __shared__ float ste1[HH];
    int tid = threadIdx.x;
    int base = blockIdx.x * 4;
    int b = base / NN;

    for (int r = 0; r < 4; ++r) {
        int row = base + r;
        if (tid < 3) spin[r][tid] = coords[row * 3 + tid];
        if (tid < DD) spin[r][3 + tid] = feats[row * DD + tid];
    }
    float tv = t[b];
    ste1[tid] = fmaxf(tv * tw1[tid] + tb1[tid], 0.0f);
    if (tid < 12) {
        int r = tid / 3, c = tid % 3;
        x[(base + r) * 3 + c] = coords[(base + r) * 3 + c];
    }
    __syncthreads();

    float a0 = pb1[tid], a1 = a0, a2 = a0, a3 = a0;
    for (int c = 0; c < 67; ++c) {
        float w = pw1[c * HH + tid];
        a0 += spin[0][c] * w; a1 += spin[1][c] * w; a2 += spin[2][c] * w; a3 += spin[3][c] * w;
    }
    sha[0][tid] = fmaxf(a0, 0.f); sha[1][tid] = fmaxf(a1, 0.f);
    sha[2][tid] = fmaxf(a2, 0.f); sha[3][tid] = fmaxf(a3, 0.f);
    __syncthreads();
    a0 = pb2[tid]; a1 = a0; a2 = a0; a3 = a0;
    for (int c = 0; c < HH; ++c) {
        float w = pw2[c * HH + tid];
        a0 += sha[0][c] * w; a1 += sha[1][c] * w; a2 += sha[2][c] * w; a3 += sha[3][c] * w;
    }
    shb[0][tid] = fmaxf(a0, 0.f); shb[1][tid] = fmaxf(a1, 0.f);
    shb[2][tid] = fmaxf(a2, 0.f); shb[3][tid] = fmaxf(a3, 0.f);
    __syncthreads();
    a0 = pb3[tid]; a1 = a0; a2 = a0; a3 = a0;
    float te = tb2[tid];
    for (int c = 0; c < HH; ++c) {
        float w = pw3[c * HH + tid];
        a0 += shb[0][c] * w; a1 += shb[1][c] * w; a2 += shb[2][c] * w; a3 += shb[3][c] * w;
        te += ste1[c] * tw2[c * HH + tid];
    }
    h[(base + 0) * HH + tid] = fmaxf(a0, 0.f) + te;
    h[(base + 1) * HH + tid] = fmaxf(a1, 0.f) + te;
    h[(base + 2) * HH + tid] = fmaxf(a2, 0.f) + te;
    h[(base + 3) * HH + tid] = fmaxf(a3, 0.f) + te;
}

// ---------------------------------------------------------------- LayerNorm + Ai/Aj
__global__ __launch_bounds__(256) void k_ln_aiaj(
    const float* __restrict__ h, const float* __restrict__ g, const float* __restrict__ bta,
    const float* __restrict__ ew1l, const float* __restrict__ eb1l,
    float* __restrict__ hn, float* __restrict__ Ai, unsigned short* __restrict__ AjB) {
    __shared__ float shn[4][HH];
    int tid = threadIdx.x, w = tid >> 6, lane = tid & 63;
    int base = blockIdx.x * 4;
    int row = base + w;

    float v[4];
    #pragma unroll
    for (int q = 0; q < 4; ++q) v[q] = h[row * HH + lane + 64 * q];
    float s = v[0] + v[1] + v[2] + v[3];
    #pragma unroll
    for (int m = 1; m < 64; m <<= 1) s += __shfl_xor(s, m);
    float mu = s * (1.0f / HH);
    float var = 0.f;
    #pragma unroll
    for (int q = 0; q < 4; ++q) { v[q] -= mu; var += v[q] * v[q]; }
    #pragma unroll
    for (int m = 1; m < 64; m <<= 1) var += __shfl_xor(var, m);
    float rstd = rsqrtf(var * (1.0f / HH) + 1e-5f);
    #pragma unroll
    for (int q = 0; q < 4; ++q) {
        int k = lane + 64 * q;
        float hv = v[q] * rstd * g[k] + bta[k];
        shn[w][k] = hv;
        hn[row * HH + k] = hv;
    }
    __syncthreads();

    float ai0 = eb1l[tid], ai1 = ai0, ai2 = ai0, ai3 = ai0;
    float aj0 = 0.f, aj1 = 0.f, aj2 = 0.f, aj3 = 0.f;
    for (int c = 0; c < HH; ++c) {
        float wi = ew1l[c * HH + tid];
        float wj = ew1l[(HH + c) * HH + tid];
        float s0 = shn[0][c], s1 = shn[1][c], s2 = shn[2][c], s3 = shn[3][c];
        ai0 += s0 * wi; ai1 += s1 * wi; ai2 += s2 * wi; ai3 += s3 * wi;
        aj0 += s0 * wj; aj1 += s1 * wj; aj2 += s2 * wj; aj3 += s3 * wj;
    }
    Ai[(base + 0) * HH + tid] = ai0; AjB[(base + 0) * HH + tid] = f2bf(aj0);
    Ai[(base + 1) * HH + tid] = ai1; AjB[(base + 1) * HH + tid] = f2bf(aj1);
    Ai[(base + 2) * HH + tid] = ai2; AjB[(base + 2) * HH + tid] = f2bf(aj2);
    Ai[(base + 3) * HH + tid] = ai3; AjB[(base + 3) * HH + tid] = f2bf(aj3);
}

// ---------------------------------------------------------------- fused edge pipeline (MFMA)
// 512 threads = 8 waves, one block per (b,i). Wave owns 32 output cols.
// B streamed from L2 via the fragment-packed layout (coalesced 1KB loads),
// register double-buffered 1 ks ahead. Working set ~100 VGPR -> no spill.
__global__ __launch_bounds__(512) void k_edge(
    const float* __restrict__ x, const float* __restrict__ Ai, const unsigned short* __restrict__ AjB,
    const float* __restrict__ wd, const float* __restrict__ eb2v,
    const unsigned short* __restrict__ ew2P, const unsigned short* __restrict__ cw1P,
    const float* __restrict__ cb1v, const float* __restrict__ cw2v, const float* __restrict__ cb2p,
    float* __restrict__ magg, float* __restrict__ xdelta) {
    __shared__ float srel[64][3];
    __shared__ float sd2[64];
    __shared__ float cwpart[8][64];
    __shared__ unsigned short s_tile[64 * 256];  // rows of 512B, XOR ((row&7)<<4)
    __shared__ unsigned short m_tile[64 * 256];

    int tid = threadIdx.x, wv = tid >> 6, lane = tid & 63;
    int g4 = lane >> 4, l15 = lane & 15;
    int colbase = wv * 32;
    int bi = blockIdx.x;
    int b = bi >> 8, i = bi & 255;
    int ni = b * NN + i;
    int bbase = b * NN;
    int bthr = (wv << 7) + (lane << 3);  // packed-B per-thread elem offset (ct<<6 elems *8? see below)

    // packed-B elem offset for (ks,ct): ((ks<<10) + (ct<<6) + (wv<<7) + lane) << 3
    // note (wv*2)<<6 = wv<<7, lane<<3 folded into bthr:
    bthr = ((wv << 7) + lane) << 3;

    // ---- per-thread resident constants
    int k0p = (tid & 31) << 3;
    float aiv[8], wdv[8];
    {
        float4v a0 = *(const float4v*)(Ai + (size_t)ni * HH + k0p);
        float4v a1 = *(const float4v*)(Ai + (size_t)ni * HH + k0p + 4);
        float4v w0 = *(const float4v*)(wd + k0p);
        float4v w1 = *(const float4v*)(wd + k0p + 4);
        #pragma unroll
        for (int e = 0; e < 4; ++e) { aiv[e] = a0[e]; aiv[4 + e] = a1[e]; wdv[e] = w0[e]; wdv[4 + e] = w1[e]; }
    }
    float eb2r[2], cb1r[2], cw2r[2];
    #pragma unroll
    for (int ct = 0; ct < 2; ++ct) {
        int col = colbase + ct * 16 + l15;
        eb2r[ct] = eb2v[col]; cb1r[ct] = cb1v[col]; cw2r[ct] = cw2v[col];
    }
    float xi0 = x[ni * 3 + 0], xi1 = x[ni * 3 + 1], xi2 = x[ni * 3 + 2];
    float cb2 = cb2p[0];

    float mg[2] = {0.f, 0.f};
    float xd0 = 0.f, xd1 = 0.f, xd2 = 0.f;

    for (int jc = 0; jc < 4; ++jc) {
        int j0 = jc * 64;
        __syncthreads();
        if (tid < 64) {
            int j = bbase + j0 + tid;
            float rx = xi0 - x[j * 3 + 0];
            float ry = xi1 - x[j * 3 + 1];
            float rz = xi2 - x[j * 3 + 2];
            srel[tid][0] = rx; srel[tid][1] = ry; srel[tid][2] = rz;
            sd2[tid] = rx * rx + ry * ry + rz * rz;
        }
        __syncthreads();

        // ---- phase 1: s tile = silu(Ai + Aj + d2*wd), 64x256 bf16
        #pragma unroll
        for (int it = 0; it < 4; ++it) {
            int row = it * 16 + (tid >> 5);
            float d2v = sd2[row];
            bf16x8 ajv = *(const bf16x8*)(AjB + ((size_t)(bbase + j0 + row) * HH + k0p));
            bf16x8 sv;
            #pragma unroll
            for (int e = 0; e < 8; ++e) {
                float vy = aiv[e] + bf2f((unsigned short)ajv[e]) + d2v * wdv[e];
                sv[e] = (short)f2bf(fsilu(vy));
            }
            unsigned off = (unsigned)(row * 512 + k0p * 2) ^ (unsigned)((row & 7) << 4);
            *reinterpret_cast<bf16x8*>(reinterpret_cast<char*>(s_tile) + off) = sv;
        }
        __syncthreads();

        // ---- phase 2: m = silu(s @ ew2 + eb2)
        {
            f32x4 acc[4][2];
            #pragma unroll
            for (int rt = 0; rt < 4; ++rt)
                #pragma unroll
                for (int ct = 0; ct < 2; ++ct) acc[rt][ct] = (f32x4){0.f, 0.f, 0.f, 0.f};
            bf16x8 bc0 = *(const bf16x8*)(ew2P + bthr);
            bf16x8 bc1 = *(const bf16x8*)(ew2P + (1 << 9) + bthr);
            #pragma unroll
            for (int ks = 0; ks < 8; ++ks) {
                bf16x8 bn0, bn1;
                if (ks < 7) {
                    bn0 = *(const bf16x8*)(ew2P + ((ks + 1) << 13) + bthr);
                    bn1 = *(const bf16x8*)(ew2P + ((ks + 1) << 13) + (1 << 9) + bthr);
                }
                int ak = ks * 32 + g4 * 8;
                bf16x8 afr[4];
                #pragma unroll
                for (int rt = 0; rt < 4; ++rt) {
                    int row = rt * 16 + l15;
                    unsigned off = (unsigned)(row * 512 + ak * 2) ^ (unsigned)((row & 7) << 4);
                    afr[rt] = *reinterpret_cast<const bf16x8*>(reinterpret_cast<const char*>(s_tile) + off);
                }
                #pragma unroll
                for (int rt = 0; rt < 4; ++rt) {
                    acc[rt][0] = __builtin_amdgcn_mfma_f32_16x16x32_bf16(afr[rt], bc0, acc[rt][0], 0, 0, 0);
                    acc[rt][1] = __builtin_amdgcn_mfma_f32_16x16x32_bf16(afr[rt], bc1, acc[rt][1], 0, 0, 0);
                }
                if (ks < 7) { bc0 = bn0; bc1 = bn1; }
            }
            #pragma unroll
            for (int ct = 0; ct < 2; ++ct) {
                int col = colbase + ct * 16 + l15;
                #pragma unroll
                for (int rt = 0; rt < 4; ++rt) {
                    #pragma unroll
                    for (int r = 0; r < 4; ++r) {
                        int row = rt * 16 + g4 * 4 + r;
                        float vy = fsilu(acc[rt][ct][r] + eb2r[ct]);
                        mg[ct] += vy;
                        unsigned off = (unsigned)(row * 512 + col * 2) ^ (unsigned)((row & 7) << 4);
                        *reinterpret_cast<unsigned short*>(reinterpret_cast<char*>(m_tile) + off) = f2bf(vy);
                    }
                }
            }
        }
        __syncthreads();

        // ---- phase 3: c = silu(m @ cw1 + cb1); cw-row-dot with cw2
        {
            f32x4 acc[4][2];
            #pragma unroll
            for (int rt = 0; rt < 4; ++rt)
                #pragma unroll
                for (int ct = 0; ct < 2; ++ct) acc[rt][ct] = (f32x4){0.f, 0.f, 0.f, 0.f};
            bf16x8 bc0 = *(const bf16x8*)(cw1P + bthr);
            bf16x8 bc1 = *(const bf16x8*)(cw1P + (1 << 9) + bthr);
            #pragma unroll
            for (int ks = 0; ks < 8; ++ks) {
                bf16x8 bn0, bn1;
                if (ks < 7) {
                    bn0 = *(const bf16x8*)(cw1P + ((ks + 1) << 13) + bthr);
                    bn1 = *(const bf16x8*)(cw1P + ((ks + 1) << 13) + (1 << 9) + bthr);
                }
                int ak = ks * 32 + g4 * 8;
                bf16x8 afr[4];
                #pragma unroll
                for (int rt = 0; rt < 4; ++rt) {
                    int row = rt * 16 + l15;
                    unsigned off = (unsigned)(row * 512 + ak * 2) ^ (unsigned)((row & 7) << 4);
                    afr[rt] = *reinterpret_cast<const bf16x8*>(reinterpret_cast<const char*>(m_tile) + off);
                }
                #pragma unroll
                for (int rt = 0; rt < 4; ++rt) {
                    acc[rt][0] = __builtin_amdgcn_mfma_f32_16x16x32_bf16(afr[rt], bc0, acc[rt][0], 0, 0, 0);
                    acc[rt][1] = __builtin_amdgcn_mfma_f32_16x16x32_bf16(afr[rt], bc1, acc[rt][1], 0, 0, 0);
                }
                if (ks < 7) { bc0 = bn0; bc1 = bn1; }
            }
            float rs[16];
            #pragma unroll
            for (int q = 0; q < 16; ++q) rs[q] = 0.f;
            #pragma unroll
            for (int ct = 0; ct < 2; ++ct) {
                #pragma unroll
                for (int rt = 0; rt < 4; ++rt)
                    #pragma unroll
                    for (int r = 0; r < 4; ++r)
                        rs[rt * 4 + r] += fsilu(acc[rt][ct][r] + cb1r[ct]) * cw2r[ct];
            }
            #pragma unroll
            for (int m = 1; m <= 8; m <<= 1)
                #pragma unroll
                for (int q = 0; q < 16; ++q) rs[q] += __shfl_xor(rs[q], m);
            if (l15 == 0) {
                int rb = g4 * 4;
                #pragma unroll
                for (int rt = 0; rt < 4; ++rt)
                    #pragma unroll
                    for (int r = 0; r < 4; ++r)
                        cwpart[wv][rt * 16 + rb + r] = rs[rt * 4 + r];
            }
        }
        __syncthreads();
        if (tid < 64) {
            float cwv = cb2;
            #pragma unroll
            for (int w = 0; w < 8; ++w) cwv += cwpart[w][tid];
            float p0 = srel[tid][0] * cwv;
            float p1 = srel[tid][1] * cwv;
            float p2 = srel[tid][2] * cwv;
            #pragma unroll
            for (int m = 1; m < 64; m <<= 1) {
                p0 += __shfl_xor(p0, m); p1 += __shfl_xor(p1, m); p2 += __shfl_xor(p2, m);
            }
            xd0 += p0; xd1 += p1; xd2 += p2;
        }
    }

    #pragma unroll
    for (int ct = 0; ct < 2; ++ct) {
        mg[ct] += __shfl_xor(mg[ct], 16);
        mg[ct] += __shfl_xor(mg[ct], 32);
    }
    if (lane < 16) {
        #pragma unroll
        for (int ct = 0; ct < 2; ++ct)
            magg[(size_t)ni * HH + colbase + ct * 16 + lane] = mg[ct];
    }
    if (tid == 0) {
        xdelta[ni * 3 + 0] = xd0 * (1.0f / NN);
        xdelta[ni * 3 + 1] = xd1 * (1.0f / NN);
        xdelta[ni * 3 + 2] = xd2 * (1.0f / NN);
    }
}

// ---------------------------------------------------------------- node update (+x update)
__global__ __launch_bounds__(256) void k_node(
    const float* __restrict__ hn, const float* __restrict__ magg,
    const float* __restrict__ nw1l, const float* __restrict__ nb1l,
    const float* __restrict__ nw2l, const float* __restrict__ nb2l,
    float* __restrict__ h, float* __restrict__ x, const float* __restrict__ xdelta) {
    __shared__ float s2[4][2 * HH];
    __shared__ float su[4][HH];
    int tid = threadIdx.x;
    int base = blockIdx.x * 4;
    for (int r = 0; r < 4; ++r) {
        s2[r][tid] = hn[(base + r) * HH + tid];
        s2[r][HH + tid] = magg[(base + r) * HH + tid];
    }
    if (tid < 12) {
        int r = tid / 3, c = tid % 3;
        x[(base + r) * 3 + c] += xdelta[(base + r) * 3 + c];
    }
    __syncthreads();
    float a0 = nb1l[tid], a1 = a0, a2 = a0, a3 = a0;
    for (int c = 0; c < 2 * HH; ++c) {
        float w = nw1l[c * HH + tid];
        a0 += s2[0][c] * w; a1 += s2[1][c] * w; a2 += s2[2][c] * w; a3 += s2[3][c] * w;
    }
    su[0][tid] = fsilu(a0); su[1][tid] = fsilu(a1); su[2][tid] = fsilu(a2); su[3][tid] = fsilu(a3);
    __syncthreads();
    float d0 = nb2l[tid], d1 = d0, d2 = d0, d3 = d0;
    for (int c = 0; c < HH; ++c) {
        float w = nw2l[c * HH + tid];
        d0 += su[0][c] * w; d1 += su[1][c] * w; d2 += su[2][c] * w; d3 += su[3][c] * w;
    }
    h[(base + 0) * HH + tid] += d0;
    h[(base + 1) * HH + tid] += d1;
    h[(base + 2) * HH + tid] += d2;
    h[(base + 3) * HH + tid] += d3;
}

// ---------------------------------------------------------------- decoder
__global__ __launch_bounds__(256) void k_decoder(
    const float* __restrict__ h,
    const float* __restrict__ dw1, const float* __restrict__ db1,
    const float* __restrict__ dw2, const float* __restrict__ db2,
    const float* __restrict__ dw3, const float* __restrict__ db3,
    float* __restrict__ out) {
    __shared__ float sh[4][HH];
    __shared__ float so1[4][HH];
    __shared__ float so2[4][HH];
    int tid = threadIdx.x;
    int base = blockIdx.x * 4;
    for (int r = 0; r < 4; ++r) sh[r][tid] = h[(base + r) * HH + tid];
    __syncthreads();
    float a0 = db1[tid], a1 = a0, a2 = a0, a3 = a0;
    for (int c = 0; c < HH; ++c) {
        float w = dw1[c * HH + tid];
        a0 += sh[0][c] * w; a1 += sh[1][c] * w; a2 += sh[2][c] * w; a3 += sh[3][c] * w;
    }
    so1[0][tid] = fmaxf(a0, 0.f); so1[1][tid] = fmaxf(a1, 0.f);
    so1[2][tid] = fmaxf(a2, 0.f); so1[3][tid] = fmaxf(a3, 0.f);
    __syncthreads();
    a0 = db2[tid]; a1 = a0; a2 = a0; a3 = a0;
    for (int c = 0; c < HH; ++c) {
        float w = dw2[c * HH + tid];
        a0 += so1[0][c] * w; a1 += so1[1][c] * w; a2 += so1[2][c] * w; a3 += so1[3][c] * w;
    }
    so2[0][tid] = fmaxf(a0, 0.f) + sh[0][tid];
    so2[1][tid] = fmaxf(a1, 0.f) + sh[1][tid];
    so2[2][tid] = fmaxf(a2, 0.f) + sh[2][tid];
    so2[3][tid] = fmaxf(a3, 0.f) + sh[3][tid];
    __syncthreads();
    if (tid < 12) {
        int r = tid / 3, c = tid % 3;
        float acc = db3[c];
        for (int k = 0; k < HH; ++k) acc += so2[r][k] * dw3[k * 3 + c];
        out[(base + r) * 3 + c] = acc;
    }
}

// ---------------------------------------------------------------- launch
extern "C" void kernel_launch(void* const* d_in, const int* in_sizes, int n_in,
                              void* d_out, int out_size, void* d_ws, size_t ws_size,
                              hipStream_t stream) {
    const float* coords = (const float*)d_in[0];
    const float* feats  = (const float*)d_in[1];
    const float* t      = (const float*)d_in[2];
    const float* pe_w1  = (const float*)d_in[3];  const float* pe_b1 = (const float*)d_in[4];
    const float* pe_w2  = (const float*)d_in[5];  const float* pe_b2 = (const float*)d_in[6];
    const float* pe_w3  = (const float*)d_in[7];  const float* pe_b3 = (const float*)d_in[8];
    const float* te_w1  = (const float*)d_in[9];  const float* te_b1 = (const float*)d_in[10];
    const float* te_w2  = (const float*)d_in[11]; const float* te_b2 = (const float*)d_in[12];
    const float* ln_g   = (const float*)d_in[13]; const float* ln_b  = (const float*)d_in[14];
    const float* ew1    = (const float*)d_in[15]; const float* eb1   = (const float*)d_in[16];
    const float* ew2    = (const float*)d_in[17]; const float* eb2   = (const float*)d_in[18];
    const float* cw1    = (const float*)d_in[19]; const float* cb1   = (const float*)d_in[20];
    const float* cw2    = (const float*)d_in[21]; const float* cb2   = (const float*)d_in[22];
    const float* nw1    = (const float*)d_in[23]; const float* nb1   = (const float*)d_in[24];
    const float* nw2    = (const float*)d_in[25]; const float* nb2   = (const float*)d_in[26];
    const float* dec_w1 = (const float*)d_in[27]; const float* dec_b1 = (const float*)d_in[28];
    const float* dec_w2 = (const float*)d_in[29]; const float* dec_b2 = (const float*)d_in[30];
    const float* dec_w3 = (const float*)d_in[31]; const float* dec_b3 = (const float*)d_in[32];

    float* ws = (float*)d_ws;
    const int RN = NB * NN * HH;  // 131072
    float* h      = ws;
    float* hn     = ws + RN;
    float* Ai     = ws + 2 * RN;
    float* magg   = ws + 3 * RN;
    float* x      = ws + 4 * RN;
    float* xdelta = ws + 4 * RN + 2048;
    unsigned short* AjB  = (unsigned short*)(ws + 4 * RN + 4096);
    unsigned short* ew2P = AjB + RN;
    unsigned short* cw1P = ew2P + LL * HH * HH;

    k_convert<<<(LL * 8192 + 511) / 512, 512, 0, stream>>>(ew2, cw1, ew2P, cw1P);
    k_encoder<<<NB * NN / 4, 256, 0, stream>>>(coords, feats, t,
        pe_w1, pe_b1, pe_w2, pe_b2, pe_w3, pe_b3, te_w1, te_b1, te_w2, te_b2, h, x);

    for (int l = 0; l < LL; ++l) {
        k_ln_aiaj<<<NB * NN / 4, 256, 0, stream>>>(h, ln_g + l * HH, ln_b + l * HH,
            ew1 + (size_t)l * 513 * HH, eb1 + l * HH, hn, Ai, AjB);
        k_edge<<<NB * NN, 512, 0, stream>>>(x, Ai, AjB,
            ew1 + ((size_t)l * 513 + 512) * HH, eb2 + l * HH,
            ew2P + (size_t)l * HH * HH, cw1P + (size_t)l * HH * HH,
            cb1 + l * HH, cw2 + l * HH, cb2 + l, magg, xdelta);
        k_node<<<NB * NN / 4, 256, 0, stream>>>(hn, magg,
            nw1 + (size_t)l * 2 * HH * HH, nb1 + l * HH,
            nw2 + (size_t)l * HH * HH, nb2 + l * HH, h, x, xdelta);
    }

    k_decoder<<<NB * NN / 4, 256, 0, stream>>>(h, dec_w1, dec_b1, dec_w2, dec_b2,
                                               dec_w3, dec_b3, (float*)d_out);
}

// Round 5
// 1160.751 us; speedup vs baseline: 1.4657x; 1.4057x over previous
//
#include <hip/hip_runtime.h>
#include <math.h>

static constexpr int NB = 2, NN = 256, HH = 256, DD = 64, LL = 6;

typedef __attribute__((ext_vector_type(8))) short bf16x8;
typedef __attribute__((ext_vector_type(4))) float f32x4;
typedef __attribute__((ext_vector_type(4))) float float4v;

__device__ __forceinline__ float fsilu(float v) { return v / (1.0f + __expf(-v)); }

__device__ __forceinline__ unsigned short f2bf(float f) {
    union { float f; unsigned int u; } x; x.f = f;
    unsigned int r = x.u + 0x7fffu + ((x.u >> 16) & 1u);
    return (unsigned short)(r >> 16);
}
__device__ __forceinline__ float bf2f(unsigned short u) {
    union { float f; unsigned int u; } x; x.u = ((unsigned int)u) << 16; return x.f;
}

// ---------------------------------------------------------------- convert (fragment-packed)
// elem[(l*8192 + (ks*16 + wv*2 + ct)*64 + lane)*8 + e]
//   = bf16( W[l][ k = ks*32+(lane>>4)*8+e ][ col = wv*32+ct*16+(lane&15) ] )
__global__ void k_convert(const float* __restrict__ ew2, const float* __restrict__ cw1,
                          unsigned short* __restrict__ ew2P, unsigned short* __restrict__ cw1P) {
    int g = blockIdx.x * blockDim.x + threadIdx.x;
    if (g >= LL * 8192) return;
    int l = g >> 13;
    int r = g & 8191;
    int lane = r & 63;
    int fidx = r >> 6;
    int ks = fidx >> 4;
    int wv = (fidx >> 1) & 7;
    int ct = fidx & 1;
    int col = wv * 32 + ct * 16 + (lane & 15);
    int k0 = ks * 32 + (lane >> 4) * 8;
    #pragma unroll
    for (int e = 0; e < 8; ++e) {
        ew2P[(size_t)g * 8 + e] = f2bf(ew2[((size_t)l * HH + k0 + e) * HH + col]);
        cw1P[(size_t)g * 8 + e] = f2bf(cw1[((size_t)l * HH + k0 + e) * HH + col]);
    }
}

// ---------------------------------------------------------------- encoder (+time emb, x init)
__global__ __launch_bounds__(256) void k_encoder(
    const float* __restrict__ coords, const float* __restrict__ feats, const float* __restrict__ t,
    const float* __restrict__ pw1, const float* __restrict__ pb1,
    const float* __restrict__ pw2, const float* __restrict__ pb2,
    const float* __restrict__ pw3, const float* __restrict__ pb3,
    const float* __restrict__ tw1, const float* __restrict__ tb1,
    const float* __restrict__ tw2, const float* __restrict__ tb2,
    float* __restrict__ h, float* __restrict__ x) {
    __shared__ float spin[4][68];
    __shared__ float sha[4][HH];
    __shared__ float shb[4][HH];
    __shared__ float ste1[HH];
    int tid = threadIdx.x;
    int base = blockIdx.x * 4;
    int b = base / NN;

    for (int r = 0; r < 4; ++r) {
        int row = base + r;
        if (tid < 3) spin[r][tid] = coords[row * 3 + tid];
        if (tid < DD) spin[r][3 + tid] = feats[row * DD + tid];
    }
    float tv = t[b];
    ste1[tid] = fmaxf(tv * tw1[tid] + tb1[tid], 0.0f);
    if (tid < 12) {
        int r = tid / 3, c = tid % 3;
        x[(base + r) * 3 + c] = coords[(base + r) * 3 + c];
    }
    __syncthreads();

    float a0 = pb1[tid], a1 = a0, a2 = a0, a3 = a0;
    for (int c = 0; c < 67; ++c) {
        float w = pw1[c * HH + tid];
        a0 += spin[0][c] * w; a1 += spin[1][c] * w; a2 += spin[2][c] * w; a3 += spin[3][c] * w;
    }
    sha[0][tid] = fmaxf(a0, 0.f); sha[1][tid] = fmaxf(a1, 0.f);
    sha[2][tid] = fmaxf(a2, 0.f); sha[3][tid] = fmaxf(a3, 0.f);
    __syncthreads();
    a0 = pb2[tid]; a1 = a0; a2 = a0; a3 = a0;
    for (int c = 0; c < HH; ++c) {
        float w = pw2[c * HH + tid];
        a0 += sha[0][c] * w; a1 += sha[1][c] * w; a2 += sha[2][c] * w; a3 += sha[3][c] * w;
    }
    shb[0][tid] = fmaxf(a0, 0.f); shb[1][tid] = fmaxf(a1, 0.f);
    shb[2][tid] = fmaxf(a2, 0.f); shb[3][tid] = fmaxf(a3, 0.f);
    __syncthreads();
    a0 = pb3[tid]; a1 = a0; a2 = a0; a3 = a0;
    float te = tb2[tid];
    for (int c = 0; c < HH; ++c) {
        float w = pw3[c * HH + tid];
        a0 += shb[0][c] * w; a1 += shb[1][c] * w; a2 += shb[2][c] * w; a3 += shb[3][c] * w;
        te += ste1[c] * tw2[c * HH + tid];
    }
    h[(base + 0) * HH + tid] = fmaxf(a0, 0.f) + te;
    h[(base + 1) * HH + tid] = fmaxf(a1, 0.f) + te;
    h[(base + 2) * HH + tid] = fmaxf(a2, 0.f) + te;
    h[(base + 3) * HH + tid] = fmaxf(a3, 0.f) + te;
}

// ---------------------------------------------------------------- LayerNorm + Ai/Aj
__global__ __launch_bounds__(256) void k_ln_aiaj(
    const float* __restrict__ h, const float* __restrict__ g, const float* __restrict__ bta,
    const float* __restrict__ ew1l, const float* __restrict__ eb1l,
    float* __restrict__ hn, float* __restrict__ Ai, unsigned short* __restrict__ AjB) {
    __shared__ float shn[4][HH];
    int tid = threadIdx.x, w = tid >> 6, lane = tid & 63;
    int base = blockIdx.x * 4;
    int row = base + w;

    float v[4];
    #pragma unroll
    for (int q = 0; q < 4; ++q) v[q] = h[row * HH + lane + 64 * q];
    float s = v[0] + v[1] + v[2] + v[3];
    #pragma unroll
    for (int m = 1; m < 64; m <<= 1) s += __shfl_xor(s, m);
    float mu = s * (1.0f / HH);
    float var = 0.f;
    #pragma unroll
    for (int q = 0; q < 4; ++q) { v[q] -= mu; var += v[q] * v[q]; }
    #pragma unroll
    for (int m = 1; m < 64; m <<= 1) var += __shfl_xor(var, m);
    float rstd = rsqrtf(var * (1.0f / HH) + 1e-5f);
    #pragma unroll
    for (int q = 0; q < 4; ++q) {
        int k = lane + 64 * q;
        float hv = v[q] * rstd * g[k] + bta[k];
        shn[w][k] = hv;
        hn[row * HH + k] = hv;
    }
    __syncthreads();

    float ai0 = eb1l[tid], ai1 = ai0, ai2 = ai0, ai3 = ai0;
    float aj0 = 0.f, aj1 = 0.f, aj2 = 0.f, aj3 = 0.f;
    for (int c = 0; c < HH; ++c) {
        float wi = ew1l[c * HH + tid];
        float wj = ew1l[(HH + c) * HH + tid];
        float s0 = shn[0][c], s1 = shn[1][c], s2 = shn[2][c], s3 = shn[3][c];
        ai0 += s0 * wi; ai1 += s1 * wi; ai2 += s2 * wi; ai3 += s3 * wi;
        aj0 += s0 * wj; aj1 += s1 * wj; aj2 += s2 * wj; aj3 += s3 * wj;
    }
    Ai[(base + 0) * HH + tid] = ai0; AjB[(base + 0) * HH + tid] = f2bf(aj0);
    Ai[(base + 1) * HH + tid] = ai1; AjB[(base + 1) * HH + tid] = f2bf(aj1);
    Ai[(base + 2) * HH + tid] = ai2; AjB[(base + 2) * HH + tid] = f2bf(aj2);
    Ai[(base + 3) * HH + tid] = ai3; AjB[(base + 3) * HH + tid] = f2bf(aj3);
}

// ---------------------------------------------------------------- fused edge pipeline (MFMA)
// 512 threads = 8 waves, one block per (b,i). Wave owns 32 output cols.
// GEMM phases split into two 32-row half-passes so peak live regs stay ~100
// (<128 cap => NO SPILL; rounds 1-4 all spilled ~110-160 MB/dispatch).
__global__ __launch_bounds__(512) void k_edge(
    const float* __restrict__ x, const float* __restrict__ Ai, const unsigned short* __restrict__ AjB,
    const float* __restrict__ wd, const float* __restrict__ eb2v,
    const unsigned short* __restrict__ ew2P, const unsigned short* __restrict__ cw1P,
    const float* __restrict__ cb1v, const float* __restrict__ cw2v, const float* __restrict__ cb2p,
    float* __restrict__ magg, float* __restrict__ xdelta) {
    __shared__ float srel[64][3];
    __shared__ float sd2[64];
    __shared__ float cwpart[8][64];
    __shared__ unsigned short s_tile[64 * 256];  // rows of 512B, XOR ((row&7)<<4)
    __shared__ unsigned short m_tile[64 * 256];

    int tid = threadIdx.x, wv = tid >> 6, lane = tid & 63;
    int g4 = lane >> 4, l15 = lane & 15;
    int colbase = wv * 32;
    int bi = blockIdx.x;
    int b = bi >> 8, i = bi & 255;
    int ni = b * NN + i;
    int bbase = b * NN;
    int bthr = ((wv << 7) + lane) << 3;  // packed-B elem offset; (ks,ct) adds (ks<<13)+(ct<<9)

    int k0p = (tid & 31) << 3;
    float aiv[8], wdv[8];
    {
        float4v a0 = *(const float4v*)(Ai + (size_t)ni * HH + k0p);
        float4v a1 = *(const float4v*)(Ai + (size_t)ni * HH + k0p + 4);
        float4v w0 = *(const float4v*)(wd + k0p);
        float4v w1 = *(const float4v*)(wd + k0p + 4);
        #pragma unroll
        for (int e = 0; e < 4; ++e) { aiv[e] = a0[e]; aiv[4 + e] = a1[e]; wdv[e] = w0[e]; wdv[4 + e] = w1[e]; }
    }
    float eb2r[2], cb1r[2], cw2r[2];
    #pragma unroll
    for (int ct = 0; ct < 2; ++ct) {
        int col = colbase + ct * 16 + l15;
        eb2r[ct] = eb2v[col]; cb1r[ct] = cb1v[col]; cw2r[ct] = cw2v[col];
    }
    float xi0 = x[ni * 3 + 0], xi1 = x[ni * 3 + 1], xi2 = x[ni * 3 + 2];
    float cb2 = cb2p[0];

    float mg[2] = {0.f, 0.f};
    float xd0 = 0.f, xd1 = 0.f, xd2 = 0.f;

    for (int jc = 0; jc < 4; ++jc) {
        int j0 = jc * 64;
        __syncthreads();
        if (tid < 64) {
            int j = bbase + j0 + tid;
            float rx = xi0 - x[j * 3 + 0];
            float ry = xi1 - x[j * 3 + 1];
            float rz = xi2 - x[j * 3 + 2];
            srel[tid][0] = rx; srel[tid][1] = ry; srel[tid][2] = rz;
            sd2[tid] = rx * rx + ry * ry + rz * rz;
        }
        __syncthreads();

        // ---- phase 1: s tile = silu(Ai + Aj + d2*wd), 64x256 bf16
        #pragma unroll
        for (int it = 0; it < 4; ++it) {
            int row = it * 16 + (tid >> 5);
            float d2v = sd2[row];
            bf16x8 ajv = *(const bf16x8*)(AjB + ((size_t)(bbase + j0 + row) * HH + k0p));
            bf16x8 sv;
            #pragma unroll
            for (int e = 0; e < 8; ++e) {
                float vy = aiv[e] + bf2f((unsigned short)ajv[e]) + d2v * wdv[e];
                sv[e] = (short)f2bf(fsilu(vy));
            }
            unsigned off = (unsigned)(row * 512 + k0p * 2) ^ (unsigned)((row & 7) << 4);
            *reinterpret_cast<bf16x8*>(reinterpret_cast<char*>(s_tile) + off) = sv;
        }
        __syncthreads();

        // ---- phase 2: m = silu(s @ ew2 + eb2), two 32-row half-passes
        for (int rh = 0; rh < 2; ++rh) {
            f32x4 acc[2][2];
            acc[0][0] = (f32x4){0.f,0.f,0.f,0.f}; acc[0][1] = (f32x4){0.f,0.f,0.f,0.f};
            acc[1][0] = (f32x4){0.f,0.f,0.f,0.f}; acc[1][1] = (f32x4){0.f,0.f,0.f,0.f};
            bf16x8 bc0 = *(const bf16x8*)(ew2P + bthr);
            bf16x8 bc1 = *(const bf16x8*)(ew2P + (1 << 9) + bthr);
            #pragma unroll
            for (int ks = 0; ks < 8; ++ks) {
                bf16x8 bn0, bn1;
                if (ks < 7) {
                    bn0 = *(const bf16x8*)(ew2P + ((ks + 1) << 13) + bthr);
                    bn1 = *(const bf16x8*)(ew2P + ((ks + 1) << 13) + (1 << 9) + bthr);
                }
                int ak = ks * 32 + g4 * 8;
                int row0 = rh * 32 + l15;
                int row1 = row0 + 16;
                unsigned off0 = (unsigned)(row0 * 512 + ak * 2) ^ (unsigned)((row0 & 7) << 4);
                unsigned off1 = (unsigned)(row1 * 512 + ak * 2) ^ (unsigned)((row1 & 7) << 4);
                bf16x8 a0 = *reinterpret_cast<const bf16x8*>(reinterpret_cast<const char*>(s_tile) + off0);
                bf16x8 a1 = *reinterpret_cast<const bf16x8*>(reinterpret_cast<const char*>(s_tile) + off1);
                acc[0][0] = __builtin_amdgcn_mfma_f32_16x16x32_bf16(a0, bc0, acc[0][0], 0, 0, 0);
                acc[0][1] = __builtin_amdgcn_mfma_f32_16x16x32_bf16(a0, bc1, acc[0][1], 0, 0, 0);
                acc[1][0] = __builtin_amdgcn_mfma_f32_16x16x32_bf16(a1, bc0, acc[1][0], 0, 0, 0);
                acc[1][1] = __builtin_amdgcn_mfma_f32_16x16x32_bf16(a1, bc1, acc[1][1], 0, 0, 0);
                if (ks < 7) { bc0 = bn0; bc1 = bn1; }
            }
            #pragma unroll
            for (int ct = 0; ct < 2; ++ct) {
                int col = colbase + ct * 16 + l15;
                #pragma unroll
                for (int rt = 0; rt < 2; ++rt) {
                    #pragma unroll
                    for (int r = 0; r < 4; ++r) {
                        int row = rh * 32 + rt * 16 + g4 * 4 + r;
                        float vy = fsilu(acc[rt][ct][r] + eb2r[ct]);
                        mg[ct] += vy;
                        unsigned off = (unsigned)(row * 512 + col * 2) ^ (unsigned)((row & 7) << 4);
                        *reinterpret_cast<unsigned short*>(reinterpret_cast<char*>(m_tile) + off) = f2bf(vy);
                    }
                }
            }
        }
        __syncthreads();

        // ---- phase 3: c = silu(m @ cw1 + cb1); cw-row-dot with cw2 (two half-passes)
        for (int rh = 0; rh < 2; ++rh) {
            f32x4 acc[2][2];
            acc[0][0] = (f32x4){0.f,0.f,0.f,0.f}; acc[0][1] = (f32x4){0.f,0.f,0.f,0.f};
            acc[1][0] = (f32x4){0.f,0.f,0.f,0.f}; acc[1][1] = (f32x4){0.f,0.f,0.f,0.f};
            bf16x8 bc0 = *(const bf16x8*)(cw1P + bthr);
            bf16x8 bc1 = *(const bf16x8*)(cw1P + (1 << 9) + bthr);
            #pragma unroll
            for (int ks = 0; ks < 8; ++ks) {
                bf16x8 bn0, bn1;
                if (ks < 7) {
                    bn0 = *(const bf16x8*)(cw1P + ((ks + 1) << 13) + bthr);
                    bn1 = *(const bf16x8*)(cw1P + ((ks + 1) << 13) + (1 << 9) + bthr);
                }
                int ak = ks * 32 + g4 * 8;
                int row0 = rh * 32 + l15;
                int row1 = row0 + 16;
                unsigned off0 = (unsigned)(row0 * 512 + ak * 2) ^ (unsigned)((row0 & 7) << 4);
                unsigned off1 = (unsigned)(row1 * 512 + ak * 2) ^ (unsigned)((row1 & 7) << 4);
                bf16x8 a0 = *reinterpret_cast<const bf16x8*>(reinterpret_cast<const char*>(m_tile) + off0);
                bf16x8 a1 = *reinterpret_cast<const bf16x8*>(reinterpret_cast<const char*>(m_tile) + off1);
                acc[0][0] = __builtin_amdgcn_mfma_f32_16x16x32_bf16(a0, bc0, acc[0][0], 0, 0, 0);
                acc[0][1] = __builtin_amdgcn_mfma_f32_16x16x32_bf16(a0, bc1, acc[0][1], 0, 0, 0);
                acc[1][0] = __builtin_amdgcn_mfma_f32_16x16x32_bf16(a1, bc0, acc[1][0], 0, 0, 0);
                acc[1][1] = __builtin_amdgcn_mfma_f32_16x16x32_bf16(a1, bc1, acc[1][1], 0, 0, 0);
                if (ks < 7) { bc0 = bn0; bc1 = bn1; }
            }
            float rs[8];
            #pragma unroll
            for (int q = 0; q < 8; ++q) rs[q] = 0.f;
            #pragma unroll
            for (int ct = 0; ct < 2; ++ct) {
                #pragma unroll
                for (int rt = 0; rt < 2; ++rt)
                    #pragma unroll
                    for (int r = 0; r < 4; ++r)
                        rs[rt * 4 + r] += fsilu(acc[rt][ct][r] + cb1r[ct]) * cw2r[ct];
            }
            #pragma unroll
            for (int m = 1; m <= 8; m <<= 1)
                #pragma unroll
                for (int q = 0; q < 8; ++q) rs[q] += __shfl_xor(rs[q], m);
            if (l15 == 0) {
                #pragma unroll
                for (int rt = 0; rt < 2; ++rt)
                    #pragma unroll
                    for (int r = 0; r < 4; ++r)
                        cwpart[wv][rh * 32 + rt * 16 + g4 * 4 + r] = rs[rt * 4 + r];
            }
        }
        __syncthreads();
        if (tid < 64) {
            float cwv = cb2;
            #pragma unroll
            for (int w = 0; w < 8; ++w) cwv += cwpart[w][tid];
            float p0 = srel[tid][0] * cwv;
            float p1 = srel[tid][1] * cwv;
            float p2 = srel[tid][2] * cwv;
            #pragma unroll
            for (int m = 1; m < 64; m <<= 1) {
                p0 += __shfl_xor(p0, m); p1 += __shfl_xor(p1, m); p2 += __shfl_xor(p2, m);
            }
            xd0 += p0; xd1 += p1; xd2 += p2;
        }
    }

    #pragma unroll
    for (int ct = 0; ct < 2; ++ct) {
        mg[ct] += __shfl_xor(mg[ct], 16);
        mg[ct] += __shfl_xor(mg[ct], 32);
    }
    if (lane < 16) {
        #pragma unroll
        for (int ct = 0; ct < 2; ++ct)
            magg[(size_t)ni * HH + colbase + ct * 16 + lane] = mg[ct];
    }
    if (tid == 0) {
        xdelta[ni * 3 + 0] = xd0 * (1.0f / NN);
        xdelta[ni * 3 + 1] = xd1 * (1.0f / NN);
        xdelta[ni * 3 + 2] = xd2 * (1.0f / NN);
    }
}

// ---------------------------------------------------------------- node update (+x update)
__global__ __launch_bounds__(256) void k_node(
    const float* __restrict__ hn, const float* __restrict__ magg,
    const float* __restrict__ nw1l, const float* __restrict__ nb1l,
    const float* __restrict__ nw2l, const float* __restrict__ nb2l,
    float* __restrict__ h, float* __restrict__ x, const float* __restrict__ xdelta) {
    __shared__ float s2[4][2 * HH];
    __shared__ float su[4][HH];
    int tid = threadIdx.x;
    int base = blockIdx.x * 4;
    for (int r = 0; r < 4; ++r) {
        s2[r][tid] = hn[(base + r) * HH + tid];
        s2[r][HH + tid] = magg[(base + r) * HH + tid];
    }
    if (tid < 12) {
        int r = tid / 3, c = tid % 3;
        x[(base + r) * 3 + c] += xdelta[(base + r) * 3 + c];
    }
    __syncthreads();
    float a0 = nb1l[tid], a1 = a0, a2 = a0, a3 = a0;
    for (int c = 0; c < 2 * HH; ++c) {
        float w = nw1l[c * HH + tid];
        a0 += s2[0][c] * w; a1 += s2[1][c] * w; a2 += s2[2][c] * w; a3 += s2[3][c] * w;
    }
    su[0][tid] = fsilu(a0); su[1][tid] = fsilu(a1); su[2][tid] = fsilu(a2); su[3][tid] = fsilu(a3);
    __syncthreads();
    float d0 = nb2l[tid], d1 = d0, d2 = d0, d3 = d0;
    for (int c = 0; c < HH; ++c) {
        float w = nw2l[c * HH + tid];
        d0 += su[0][c] * w; d1 += su[1][c] * w; d2 += su[2][c] * w; d3 += su[3][c] * w;
    }
    h[(base + 0) * HH + tid] += d0;
    h[(base + 1) * HH + tid] += d1;
    h[(base + 2) * HH + tid] += d2;
    h[(base + 3) * HH + tid] += d3;
}

// ---------------------------------------------------------------- decoder
__global__ __launch_bounds__(256) void k_decoder(
    const float* __restrict__ h,
    const float* __restrict__ dw1, const float* __restrict__ db1,
    const float* __restrict__ dw2, const float* __restrict__ db2,
    const float* __restrict__ dw3, const float* __restrict__ db3,
    float* __restrict__ out) {
    __shared__ float sh[4][HH];
    __shared__ float so1[4][HH];
    __shared__ float so2[4][HH];
    int tid = threadIdx.x;
    int base = blockIdx.x * 4;
    for (int r = 0; r < 4; ++r) sh[r][tid] = h[(base + r) * HH + tid];
    __syncthreads();
    float a0 = db1[tid], a1 = a0, a2 = a0, a3 = a0;
    for (int c = 0; c < HH; ++c) {
        float w = dw1[c * HH + tid];
        a0 += sh[0][c] * w; a1 += sh[1][c] * w; a2 += sh[2][c] * w; a3 += sh[3][c] * w;
    }
    so1[0][tid] = fmaxf(a0, 0.f); so1[1][tid] = fmaxf(a1, 0.f);
    so1[2][tid] = fmaxf(a2, 0.f); so1[3][tid] = fmaxf(a3, 0.f);
    __syncthreads();
    a0 = db2[tid]; a1 = a0; a2 = a0; a3 = a0;
    for (int c = 0; c < HH; ++c) {
        float w = dw2[c * HH + tid];
        a0 += so1[0][c] * w; a1 += so1[1][c] * w; a2 += so1[2][c] * w; a3 += so1[3][c] * w;
    }
    so2[0][tid] = fmaxf(a0, 0.f) + sh[0][tid];
    so2[1][tid] = fmaxf(a1, 0.f) + sh[1][tid];
    so2[2][tid] = fmaxf(a2, 0.f) + sh[2][tid];
    so2[3][tid] = fmaxf(a3, 0.f) + sh[3][tid];
    __syncthreads();
    if (tid < 12) {
        int r = tid / 3, c = tid % 3;
        float acc = db3[c];
        for (int k = 0; k < HH; ++k) acc += so2[r][k] * dw3[k * 3 + c];
        out[(base + r) * 3 + c] = acc;
    }
}

// ---------------------------------------------------------------- launch
extern "C" void kernel_launch(void* const* d_in, const int* in_sizes, int n_in,
                              void* d_out, int out_size, void* d_ws, size_t ws_size,
                              hipStream_t stream) {
    const float* coords = (const float*)d_in[0];
    const float* feats  = (const float*)d_in[1];
    const float* t      = (const float*)d_in[2];
    const float* pe_w1  = (const float*)d_in[3];  const float* pe_b1 = (const float*)d_in[4];
    const float* pe_w2  = (const float*)d_in[5];  const float* pe_b2 = (const float*)d_in[6];
    const float* pe_w3  = (const float*)d_in[7];  const float* pe_b3 = (const float*)d_in[8];
    const float* te_w1  = (const float*)d_in[9];  const float* te_b1 = (const float*)d_in[10];
    const float* te_w2  = (const float*)d_in[11]; const float* te_b2 = (const float*)d_in[12];
    const float* ln_g   = (const float*)d_in[13]; const float* ln_b  = (const float*)d_in[14];
    const float* ew1    = (const float*)d_in[15]; const float* eb1   = (const float*)d_in[16];
    const float* ew2    = (const float*)d_in[17]; const float* eb2   = (const float*)d_in[18];
    const float* cw1    = (const float*)d_in[19]; const float* cb1   = (const float*)d_in[20];
    const float* cw2    = (const float*)d_in[21]; const float* cb2   = (const float*)d_in[22];
    const float* nw1    = (const float*)d_in[23]; const float* nb1   = (const float*)d_in[24];
    const float* nw2    = (const float*)d_in[25]; const float* nb2   = (const float*)d_in[26];
    const float* dec_w1 = (const float*)d_in[27]; const float* dec_b1 = (const float*)d_in[28];
    const float* dec_w2 = (const float*)d_in[29]; const float* dec_b2 = (const float*)d_in[30];
    const float* dec_w3 = (const float*)d_in[31]; const float* dec_b3 = (const float*)d_in[32];

    float* ws = (float*)d_ws;
    const int RN = NB * NN * HH;  // 131072
    float* h      = ws;
    float* hn     = ws + RN;
    float* Ai     = ws + 2 * RN;
    float* magg   = ws + 3 * RN;
    float* x      = ws + 4 * RN;
    float* xdelta = ws + 4 * RN + 2048;
    unsigned short* AjB  = (unsigned short*)(ws + 4 * RN + 4096);
    unsigned short* ew2P = AjB + RN;
    unsigned short* cw1P = ew2P + LL * HH * HH;

    k_convert<<<(LL * 8192 + 511) / 512, 512, 0, stream>>>(ew2, cw1, ew2P, cw1P);
    k_encoder<<<NB * NN / 4, 256, 0, stream>>>(coords, feats, t,
        pe_w1, pe_b1, pe_w2, pe_b2, pe_w3, pe_b3, te_w1, te_b1, te_w2, te_b2, h, x);

    for (int l = 0; l < LL; ++l) {
        k_ln_aiaj<<<NB * NN / 4, 256, 0, stream>>>(h, ln_g + l * HH, ln_b + l * HH,
            ew1 + (size_t)l * 513 * HH, eb1 + l * HH, hn, Ai, AjB);
        k_edge<<<NB * NN, 512, 0, stream>>>(x, Ai, AjB,
            ew1 + ((size_t)l * 513 + 512) * HH, eb2 + l * HH,
            ew2P + (size_t)l * HH * HH, cw1P + (size_t)l * HH * HH,
            cb1 + l * HH, cw2 + l * HH, cb2 + l, magg, xdelta);
        k_node<<<NB * NN / 4, 256, 0, stream>>>(hn, magg,
            nw1 + (size_t)l * 2 * HH * HH, nb1 + l * HH,
            nw2 + (size_t)l * HH * HH, nb2 + l * HH, h, x, xdelta);
    }

    k_decoder<<<NB * NN / 4, 256, 0, stream>>>(h, dec_w1, dec_b1, dec_w2, dec_b2,
                                               dec_w3, dec_b3, (float*)d_out);
}

// Round 6
// 942.939 us; speedup vs baseline: 1.8043x; 1.2310x over previous
//
#include <hip/hip_runtime.h>
#include <math.h>

static constexpr int NB = 2, NN = 256, HH = 256, DD = 64, LL = 6;

typedef __attribute__((ext_vector_type(8))) short bf16x8;
typedef __attribute__((ext_vector_type(4))) float f32x4;
typedef __attribute__((ext_vector_type(4))) float float4v;

__device__ __forceinline__ float fsilu(float v) { return v / (1.0f + __expf(-v)); }

__device__ __forceinline__ unsigned short f2bf(float f) {
    union { float f; unsigned int u; } x; x.f = f;
    unsigned int r = x.u + 0x7fffu + ((x.u >> 16) & 1u);
    return (unsigned short)(r >> 16);
}
__device__ __forceinline__ float bf2f(unsigned short u) {
    union { float f; unsigned int u; } x; x.u = ((unsigned int)u) << 16; return x.f;
}

// ---------------------------------------------------------------- convert (fragment-packed)
// elem[(l*8192 + (ks*16 + wv*2 + ct)*64 + lane)*8 + e]
//   = bf16( W[l][ k = ks*32+(lane>>4)*8+e ][ col = wv*32+ct*16+(lane&15) ] )
__global__ void k_convert(const float* __restrict__ ew2, const float* __restrict__ cw1,
                          unsigned short* __restrict__ ew2P, unsigned short* __restrict__ cw1P) {
    int g = blockIdx.x * blockDim.x + threadIdx.x;
    if (g >= LL * 8192) return;
    int l = g >> 13;
    int r = g & 8191;
    int lane = r & 63;
    int fidx = r >> 6;
    int ks = fidx >> 4;
    int wv = (fidx >> 1) & 7;
    int ct = fidx & 1;
    int col = wv * 32 + ct * 16 + (lane & 15);
    int k0 = ks * 32 + (lane >> 4) * 8;
    #pragma unroll
    for (int e = 0; e < 8; ++e) {
        ew2P[(size_t)g * 8 + e] = f2bf(ew2[((size_t)l * HH + k0 + e) * HH + col]);
        cw1P[(size_t)g * 8 + e] = f2bf(cw1[((size_t)l * HH + k0 + e) * HH + col]);
    }
}

// ---------------------------------------------------------------- encoder (+time emb, x init)
__global__ __launch_bounds__(256) void k_encoder(
    const float* __restrict__ coords, const float* __restrict__ feats, const float* __restrict__ t,
    const float* __restrict__ pw1, const float* __restrict__ pb1,
    const float* __restrict__ pw2, const float* __restrict__ pb2,
    const float* __restrict__ pw3, const float* __restrict__ pb3,
    const float* __restrict__ tw1, const float* __restrict__ tb1,
    const float* __restrict__ tw2, const float* __restrict__ tb2,
    float* __restrict__ h, float* __restrict__ x) {
    __shared__ float spin[4][68];
    __shared__ float sha[4][HH];
    __shared__ float shb[4][HH];
    __shared__ float ste1[HH];
    int tid = threadIdx.x;
    int base = blockIdx.x * 4;
    int b = base / NN;

    for (int r = 0; r < 4; ++r) {
        int row = base + r;
        if (tid < 3) spin[r][tid] = coords[row * 3 + tid];
        if (tid < DD) spin[r][3 + tid] = feats[row * DD + tid];
    }
    float tv = t[b];
    ste1[tid] = fmaxf(tv * tw1[tid] + tb1[tid], 0.0f);
    if (tid < 12) {
        int r = tid / 3, c = tid % 3;
        x[(base + r) * 3 + c] = coords[(base + r) * 3 + c];
    }
    __syncthreads();

    float a0 = pb1[tid], a1 = a0, a2 = a0, a3 = a0;
    for (int c = 0; c < 67; ++c) {
        float w = pw1[c * HH + tid];
        a0 += spin[0][c] * w; a1 += spin[1][c] * w; a2 += spin[2][c] * w; a3 += spin[3][c] * w;
    }
    sha[0][tid] = fmaxf(a0, 0.f); sha[1][tid] = fmaxf(a1, 0.f);
    sha[2][tid] = fmaxf(a2, 0.f); sha[3][tid] = fmaxf(a3, 0.f);
    __syncthreads();
    a0 = pb2[tid]; a1 = a0; a2 = a0; a3 = a0;
    for (int c = 0; c < HH; ++c) {
        float w = pw2[c * HH + tid];
        a0 += sha[0][c] * w; a1 += sha[1][c] * w; a2 += sha[2][c] * w; a3 += sha[3][c] * w;
    }
    shb[0][tid] = fmaxf(a0, 0.f); shb[1][tid] = fmaxf(a1, 0.f);
    shb[2][tid] = fmaxf(a2, 0.f); shb[3][tid] = fmaxf(a3, 0.f);
    __syncthreads();
    a0 = pb3[tid]; a1 = a0; a2 = a0; a3 = a0;
    float te = tb2[tid];
    for (int c = 0; c < HH; ++c) {
        float w = pw3[c * HH + tid];
        a0 += shb[0][c] * w; a1 += shb[1][c] * w; a2 += shb[2][c] * w; a3 += shb[3][c] * w;
        te += ste1[c] * tw2[c * HH + tid];
    }
    h[(base + 0) * HH + tid] = fmaxf(a0, 0.f) + te;
    h[(base + 1) * HH + tid] = fmaxf(a1, 0.f) + te;
    h[(base + 2) * HH + tid] = fmaxf(a2, 0.f) + te;
    h[(base + 3) * HH + tid] = fmaxf(a3, 0.f) + te;
}

// ---------------------------------------------------------------- LayerNorm + Ai/Aj
__global__ __launch_bounds__(256) void k_ln_aiaj(
    const float* __restrict__ h, const float* __restrict__ g, const float* __restrict__ bta,
    const float* __restrict__ ew1l, const float* __restrict__ eb1l,
    float* __restrict__ hn, float* __restrict__ Ai, unsigned short* __restrict__ AjB) {
    __shared__ float shn[4][HH];
    int tid = threadIdx.x, w = tid >> 6, lane = tid & 63;
    int base = blockIdx.x * 4;
    int row = base + w;

    float v[4];
    #pragma unroll
    for (int q = 0; q < 4; ++q) v[q] = h[row * HH + lane + 64 * q];
    float s = v[0] + v[1] + v[2] + v[3];
    #pragma unroll
    for (int m = 1; m < 64; m <<= 1) s += __shfl_xor(s, m);
    float mu = s * (1.0f / HH);
    float var = 0.f;
    #pragma unroll
    for (int q = 0; q < 4; ++q) { v[q] -= mu; var += v[q] * v[q]; }
    #pragma unroll
    for (int m = 1; m < 64; m <<= 1) var += __shfl_xor(var, m);
    float rstd = rsqrtf(var * (1.0f / HH) + 1e-5f);
    #pragma unroll
    for (int q = 0; q < 4; ++q) {
        int k = lane + 64 * q;
        float hv = v[q] * rstd * g[k] + bta[k];
        shn[w][k] = hv;
        hn[row * HH + k] = hv;
    }
    __syncthreads();

    float ai0 = eb1l[tid], ai1 = ai0, ai2 = ai0, ai3 = ai0;
    float aj0 = 0.f, aj1 = 0.f, aj2 = 0.f, aj3 = 0.f;
    for (int c = 0; c < HH; ++c) {
        float wi = ew1l[c * HH + tid];
        float wj = ew1l[(HH + c) * HH + tid];
        float s0 = shn[0][c], s1 = shn[1][c], s2 = shn[2][c], s3 = shn[3][c];
        ai0 += s0 * wi; ai1 += s1 * wi; ai2 += s2 * wi; ai3 += s3 * wi;
        aj0 += s0 * wj; aj1 += s1 * wj; aj2 += s2 * wj; aj3 += s3 * wj;
    }
    Ai[(base + 0) * HH + tid] = ai0; AjB[(base + 0) * HH + tid] = f2bf(aj0);
    Ai[(base + 1) * HH + tid] = ai1; AjB[(base + 1) * HH + tid] = f2bf(aj1);
    Ai[(base + 2) * HH + tid] = ai2; AjB[(base + 2) * HH + tid] = f2bf(aj2);
    Ai[(base + 3) * HH + tid] = ai3; AjB[(base + 3) * HH + tid] = f2bf(aj3);
}

// ---------------------------------------------------------------- fused edge pipeline (MFMA)
// 512 threads = 8 waves, one block per (b,i). Wave owns 32 output cols.
// __launch_bounds__(512, 1): hipcc treats arg2 as min BLOCKS/CU (round-2
// evidence: arg2=2 -> exactly 128-reg cap = 4 waves/SIMD). With 1 block/CU
// min, budget = 256 VGPR -> the ~180-reg working set must not spill.
// Runtime occupancy stays 2 blocks/CU (LDS 68.6KB, VGPR <= 256).
// #pragma unroll 1 on jc keeps live ranges from merging across iterations.
__global__ __launch_bounds__(512, 1) void k_edge(
    const float* __restrict__ x, const float* __restrict__ Ai, const unsigned short* __restrict__ AjB,
    const float* __restrict__ wd, const float* __restrict__ eb2v,
    const unsigned short* __restrict__ ew2P, const unsigned short* __restrict__ cw1P,
    const float* __restrict__ cb1v, const float* __restrict__ cw2v, const float* __restrict__ cb2p,
    float* __restrict__ magg, float* __restrict__ xdelta) {
    __shared__ float srel[64][3];
    __shared__ float sd2[64];
    __shared__ float cwpart[8][64];
    __shared__ unsigned short s_tile[64 * 256];  // rows of 512B, XOR ((row&7)<<4)
    __shared__ unsigned short m_tile[64 * 256];

    int tid = threadIdx.x, wv = tid >> 6, lane = tid & 63;
    int g4 = lane >> 4, l15 = lane & 15;
    int colbase = wv * 32;
    int bi = blockIdx.x;
    int b = bi >> 8, i = bi & 255;
    int ni = b * NN + i;
    int bbase = b * NN;
    int bthr = ((wv << 7) + lane) << 3;  // packed-B elem offset; (ks,ct) adds (ks<<13)+(ct<<9)

    int k0p = (tid & 31) << 3;
    float aiv[8], wdv[8];
    {
        float4v a0 = *(const float4v*)(Ai + (size_t)ni * HH + k0p);
        float4v a1 = *(const float4v*)(Ai + (size_t)ni * HH + k0p + 4);
        float4v w0 = *(const float4v*)(wd + k0p);
        float4v w1 = *(const float4v*)(wd + k0p + 4);
        #pragma unroll
        for (int e = 0; e < 4; ++e) { aiv[e] = a0[e]; aiv[4 + e] = a1[e]; wdv[e] = w0[e]; wdv[4 + e] = w1[e]; }
    }
    float eb2r[2], cb1r[2], cw2r[2];
    #pragma unroll
    for (int ct = 0; ct < 2; ++ct) {
        int col = colbase + ct * 16 + l15;
        eb2r[ct] = eb2v[col]; cb1r[ct] = cb1v[col]; cw2r[ct] = cw2v[col];
    }
    float xi0 = x[ni * 3 + 0], xi1 = x[ni * 3 + 1], xi2 = x[ni * 3 + 2];
    float cb2 = cb2p[0];

    float mg[2] = {0.f, 0.f};
    float xd0 = 0.f, xd1 = 0.f, xd2 = 0.f;

    #pragma unroll 1
    for (int jc = 0; jc < 4; ++jc) {
        int j0 = jc * 64;
        __syncthreads();
        if (tid < 64) {
            int j = bbase + j0 + tid;
            float rx = xi0 - x[j * 3 + 0];
            float ry = xi1 - x[j * 3 + 1];
            float rz = xi2 - x[j * 3 + 2];
            srel[tid][0] = rx; srel[tid][1] = ry; srel[tid][2] = rz;
            sd2[tid] = rx * rx + ry * ry + rz * rz;
        }
        __syncthreads();

        // ---- phase 1: s tile = silu(Ai + Aj + d2*wd), 64x256 bf16
        #pragma unroll
        for (int it = 0; it < 4; ++it) {
            int row = it * 16 + (tid >> 5);
            float d2v = sd2[row];
            bf16x8 ajv = *(const bf16x8*)(AjB + ((size_t)(bbase + j0 + row) * HH + k0p));
            bf16x8 sv;
            #pragma unroll
            for (int e = 0; e < 8; ++e) {
                float vy = aiv[e] + bf2f((unsigned short)ajv[e]) + d2v * wdv[e];
                sv[e] = (short)f2bf(fsilu(vy));
            }
            unsigned off = (unsigned)(row * 512 + k0p * 2) ^ (unsigned)((row & 7) << 4);
            *reinterpret_cast<bf16x8*>(reinterpret_cast<char*>(s_tile) + off) = sv;
        }
        __syncthreads();

        // ---- phase 2: m = silu(s @ ew2 + eb2), two 32-row half-passes
        #pragma unroll 1
        for (int rh = 0; rh < 2; ++rh) {
            f32x4 acc[2][2];
            acc[0][0] = (f32x4){0.f,0.f,0.f,0.f}; acc[0][1] = (f32x4){0.f,0.f,0.f,0.f};
            acc[1][0] = (f32x4){0.f,0.f,0.f,0.f}; acc[1][1] = (f32x4){0.f,0.f,0.f,0.f};
            bf16x8 bc0 = *(const bf16x8*)(ew2P + bthr);
            bf16x8 bc1 = *(const bf16x8*)(ew2P + (1 << 9) + bthr);
            #pragma unroll
            for (int ks = 0; ks < 8; ++ks) {
                bf16x8 bn0, bn1;
                if (ks < 7) {
                    bn0 = *(const bf16x8*)(ew2P + ((ks + 1) << 13) + bthr);
                    bn1 = *(const bf16x8*)(ew2P + ((ks + 1) << 13) + (1 << 9) + bthr);
                }
                int ak = ks * 32 + g4 * 8;
                int row0 = rh * 32 + l15;
                int row1 = row0 + 16;
                unsigned off0 = (unsigned)(row0 * 512 + ak * 2) ^ (unsigned)((row0 & 7) << 4);
                unsigned off1 = (unsigned)(row1 * 512 + ak * 2) ^ (unsigned)((row1 & 7) << 4);
                bf16x8 a0 = *reinterpret_cast<const bf16x8*>(reinterpret_cast<const char*>(s_tile) + off0);
                bf16x8 a1 = *reinterpret_cast<const bf16x8*>(reinterpret_cast<const char*>(s_tile) + off1);
                acc[0][0] = __builtin_amdgcn_mfma_f32_16x16x32_bf16(a0, bc0, acc[0][0], 0, 0, 0);
                acc[0][1] = __builtin_amdgcn_mfma_f32_16x16x32_bf16(a0, bc1, acc[0][1], 0, 0, 0);
                acc[1][0] = __builtin_amdgcn_mfma_f32_16x16x32_bf16(a1, bc0, acc[1][0], 0, 0, 0);
                acc[1][1] = __builtin_amdgcn_mfma_f32_16x16x32_bf16(a1, bc1, acc[1][1], 0, 0, 0);
                if (ks < 7) { bc0 = bn0; bc1 = bn1; }
            }
            #pragma unroll
            for (int ct = 0; ct < 2; ++ct) {
                int col = colbase + ct * 16 + l15;
                #pragma unroll
                for (int rt = 0; rt < 2; ++rt) {
                    #pragma unroll
                    for (int r = 0; r < 4; ++r) {
                        int row = rh * 32 + rt * 16 + g4 * 4 + r;
                        float vy = fsilu(acc[rt][ct][r] + eb2r[ct]);
                        mg[ct] += vy;
                        unsigned off = (unsigned)(row * 512 + col * 2) ^ (unsigned)((row & 7) << 4);
                        *reinterpret_cast<unsigned short*>(reinterpret_cast<char*>(m_tile) + off) = f2bf(vy);
                    }
                }
            }
        }
        __syncthreads();

        // ---- phase 3: c = silu(m @ cw1 + cb1); cw-row-dot with cw2 (two half-passes)
        #pragma unroll 1
        for (int rh = 0; rh < 2; ++rh) {
            f32x4 acc[2][2];
            acc[0][0] = (f32x4){0.f,0.f,0.f,0.f}; acc[0][1] = (f32x4){0.f,0.f,0.f,0.f};
            acc[1][0] = (f32x4){0.f,0.f,0.f,0.f}; acc[1][1] = (f32x4){0.f,0.f,0.f,0.f};
            bf16x8 bc0 = *(const bf16x8*)(cw1P + bthr);
            bf16x8 bc1 = *(const bf16x8*)(cw1P + (1 << 9) + bthr);
            #pragma unroll
            for (int ks = 0; ks < 8; ++ks) {
                bf16x8 bn0, bn1;
                if (ks < 7) {
                    bn0 = *(const bf16x8*)(cw1P + ((ks + 1) << 13) + bthr);
                    bn1 = *(const bf16x8*)(cw1P + ((ks + 1) << 13) + (1 << 9) + bthr);
                }
                int ak = ks * 32 + g4 * 8;
                int row0 = rh * 32 + l15;
                int row1 = row0 + 16;
                unsigned off0 = (unsigned)(row0 * 512 + ak * 2) ^ (unsigned)((row0 & 7) << 4);
                unsigned off1 = (unsigned)(row1 * 512 + ak * 2) ^ (unsigned)((row1 & 7) << 4);
                bf16x8 a0 = *reinterpret_cast<const bf16x8*>(reinterpret_cast<const char*>(m_tile) + off0);
                bf16x8 a1 = *reinterpret_cast<const bf16x8*>(reinterpret_cast<const char*>(m_tile) + off1);
                acc[0][0] = __builtin_amdgcn_mfma_f32_16x16x32_bf16(a0, bc0, acc[0][0], 0, 0, 0);
                acc[0][1] = __builtin_amdgcn_mfma_f32_16x16x32_bf16(a0, bc1, acc[0][1], 0, 0, 0);
                acc[1][0] = __builtin_amdgcn_mfma_f32_16x16x32_bf16(a1, bc0, acc[1][0], 0, 0, 0);
                acc[1][1] = __builtin_amdgcn_mfma_f32_16x16x32_bf16(a1, bc1, acc[1][1], 0, 0, 0);
                if (ks < 7) { bc0 = bn0; bc1 = bn1; }
            }
            float rs[8];
            #pragma unroll
            for (int q = 0; q < 8; ++q) rs[q] = 0.f;
            #pragma unroll
            for (int ct = 0; ct < 2; ++ct) {
                #pragma unroll
                for (int rt = 0; rt < 2; ++rt)
                    #pragma unroll
                    for (int r = 0; r < 4; ++r)
                        rs[rt * 4 + r] += fsilu(acc[rt][ct][r] + cb1r[ct]) * cw2r[ct];
            }
            #pragma unroll
            for (int m = 1; m <= 8; m <<= 1)
                #pragma unroll
                for (int q = 0; q < 8; ++q) rs[q] += __shfl_xor(rs[q], m);
            if (l15 == 0) {
                #pragma unroll
                for (int rt = 0; rt < 2; ++rt)
                    #pragma unroll
                    for (int r = 0; r < 4; ++r)
                        cwpart[wv][rh * 32 + rt * 16 + g4 * 4 + r] = rs[rt * 4 + r];
            }
        }
        __syncthreads();
        if (tid < 64) {
            float cwv = cb2;
            #pragma unroll
            for (int w = 0; w < 8; ++w) cwv += cwpart[w][tid];
            float p0 = srel[tid][0] * cwv;
            float p1 = srel[tid][1] * cwv;
            float p2 = srel[tid][2] * cwv;
            #pragma unroll
            for (int m = 1; m < 64; m <<= 1) {
                p0 += __shfl_xor(p0, m); p1 += __shfl_xor(p1, m); p2 += __shfl_xor(p2, m);
            }
            xd0 += p0; xd1 += p1; xd2 += p2;
        }
    }

    #pragma unroll
    for (int ct = 0; ct < 2; ++ct) {
        mg[ct] += __shfl_xor(mg[ct], 16);
        mg[ct] += __shfl_xor(mg[ct], 32);
    }
    if (lane < 16) {
        #pragma unroll
        for (int ct = 0; ct < 2; ++ct)
            magg[(size_t)ni * HH + colbase + ct * 16 + lane] = mg[ct];
    }
    if (tid == 0) {
        xdelta[ni * 3 + 0] = xd0 * (1.0f / NN);
        xdelta[ni * 3 + 1] = xd1 * (1.0f / NN);
        xdelta[ni * 3 + 2] = xd2 * (1.0f / NN);
    }
}

// ---------------------------------------------------------------- node update (+x update)
__global__ __launch_bounds__(256) void k_node(
    const float* __restrict__ hn, const float* __restrict__ magg,
    const float* __restrict__ nw1l, const float* __restrict__ nb1l,
    const float* __restrict__ nw2l, const float* __restrict__ nb2l,
    float* __restrict__ h, float* __restrict__ x, const float* __restrict__ xdelta) {
    __shared__ float s2[4][2 * HH];
    __shared__ float su[4][HH];
    int tid = threadIdx.x;
    int base = blockIdx.x * 4;
    for (int r = 0; r < 4; ++r) {
        s2[r][tid] = hn[(base + r) * HH + tid];
        s2[r][HH + tid] = magg[(base + r) * HH + tid];
    }
    if (tid < 12) {
        int r = tid / 3, c = tid % 3;
        x[(base + r) * 3 + c] += xdelta[(base + r) * 3 + c];
    }
    __syncthreads();
    float a0 = nb1l[tid], a1 = a0, a2 = a0, a3 = a0;
    for (int c = 0; c < 2 * HH; ++c) {
        float w = nw1l[c * HH + tid];
        a0 += s2[0][c] * w; a1 += s2[1][c] * w; a2 += s2[2][c] * w; a3 += s2[3][c] * w;
    }
    su[0][tid] = fsilu(a0); su[1][tid] = fsilu(a1); su[2][tid] = fsilu(a2); su[3][tid] = fsilu(a3);
    __syncthreads();
    float d0 = nb2l[tid], d1 = d0, d2 = d0, d3 = d0;
    for (int c = 0; c < HH; ++c) {
        float w = nw2l[c * HH + tid];
        d0 += su[0][c] * w; d1 += su[1][c] * w; d2 += su[2][c] * w; d3 += su[3][c] * w;
    }
    h[(base + 0) * HH + tid] += d0;
    h[(base + 1) * HH + tid] += d1;
    h[(base + 2) * HH + tid] += d2;
    h[(base + 3) * HH + tid] += d3;
}

// ---------------------------------------------------------------- decoder
__global__ __launch_bounds__(256) void k_decoder(
    const float* __restrict__ h,
    const float* __restrict__ dw1, const float* __restrict__ db1,
    const float* __restrict__ dw2, const float* __restrict__ db2,
    const float* __restrict__ dw3, const float* __restrict__ db3,
    float* __restrict__ out) {
    __shared__ float sh[4][HH];
    __shared__ float so1[4][HH];
    __shared__ float so2[4][HH];
    int tid = threadIdx.x;
    int base = blockIdx.x * 4;
    for (int r = 0; r < 4; ++r) sh[r][tid] = h[(base + r) * HH + tid];
    __syncthreads();
    float a0 = db1[tid], a1 = a0, a2 = a0, a3 = a0;
    for (int c = 0; c < HH; ++c) {
        float w = dw1[c * HH + tid];
        a0 += sh[0][c] * w; a1 += sh[1][c] * w; a2 += sh[2][c] * w; a3 += sh[3][c] * w;
    }
    so1[0][tid] = fmaxf(a0, 0.f); so1[1][tid] = fmaxf(a1, 0.f);
    so1[2][tid] = fmaxf(a2, 0.f); so1[3][tid] = fmaxf(a3, 0.f);
    __syncthreads();
    a0 = db2[tid]; a1 = a0; a2 = a0; a3 = a0;
    for (int c = 0; c < HH; ++c) {
        float w = dw2[c * HH + tid];
        a0 += so1[0][c] * w; a1 += so1[1][c] * w; a2 += so1[2][c] * w; a3 += so1[3][c] * w;
    }
    so2[0][tid] = fmaxf(a0, 0.f) + sh[0][tid];
    so2[1][tid] = fmaxf(a1, 0.f) + sh[1][tid];
    so2[2][tid] = fmaxf(a2, 0.f) + sh[2][tid];
    so2[3][tid] = fmaxf(a3, 0.f) + sh[3][tid];
    __syncthreads();
    if (tid < 12) {
        int r = tid / 3, c = tid % 3;
        float acc = db3[c];
        for (int k = 0; k < HH; ++k) acc += so2[r][k] * dw3[k * 3 + c];
        out[(base + r) * 3 + c] = acc;
    }
}

// ---------------------------------------------------------------- launch
extern "C" void kernel_launch(void* const* d_in, const int* in_sizes, int n_in,
                              void* d_out, int out_size, void* d_ws, size_t ws_size,
                              hipStream_t stream) {
    const float* coords = (const float*)d_in[0];
    const float* feats  = (const float*)d_in[1];
    const float* t      = (const float*)d_in[2];
    const float* pe_w1  = (const float*)d_in[3];  const float* pe_b1 = (const float*)d_in[4];
    const float* pe_w2  = (const float*)d_in[5];  const float* pe_b2 = (const float*)d_in[6];
    const float* pe_w3  = (const float*)d_in[7];  const float* pe_b3 = (const float*)d_in[8];
    const float* te_w1  = (const float*)d_in[9];  const float* te_b1 = (const float*)d_in[10];
    const float* te_w2  = (const float*)d_in[11]; const float* te_b2 = (const float*)d_in[12];
    const float* ln_g   = (const float*)d_in[13]; const float* ln_b  = (const float*)d_in[14];
    const float* ew1    = (const float*)d_in[15]; const float* eb1   = (const float*)d_in[16];
    const float* ew2    = (const float*)d_in[17]; const float* eb2   = (const float*)d_in[18];
    const float* cw1    = (const float*)d_in[19]; const float* cb1   = (const float*)d_in[20];
    const float* cw2    = (const float*)d_in[21]; const float* cb2   = (const float*)d_in[22];
    const float* nw1    = (const float*)d_in[23]; const float* nb1   = (const float*)d_in[24];
    const float* nw2    = (const float*)d_in[25]; const float* nb2   = (const float*)d_in[26];
    const float* dec_w1 = (const float*)d_in[27]; const float* dec_b1 = (const float*)d_in[28];
    const float* dec_w2 = (const float*)d_in[29]; const float* dec_b2 = (const float*)d_in[30];
    const float* dec_w3 = (const float*)d_in[31]; const float* dec_b3 = (const float*)d_in[32];

    float* ws = (float*)d_ws;
    const int RN = NB * NN * HH;  // 131072
    float* h      = ws;
    float* hn     = ws + RN;
    float* Ai     = ws + 2 * RN;
    float* magg   = ws + 3 * RN;
    float* x      = ws + 4 * RN;
    float* xdelta = ws + 4 * RN + 2048;
    unsigned short* AjB  = (unsigned short*)(ws + 4 * RN + 4096);
    unsigned short* ew2P = AjB + RN;
    unsigned short* cw1P = ew2P + LL * HH * HH;

    k_convert<<<(LL * 8192 + 511) / 512, 512, 0, stream>>>(ew2, cw1, ew2P, cw1P);
    k_encoder<<<NB * NN / 4, 256, 0, stream>>>(coords, feats, t,
        pe_w1, pe_b1, pe_w2, pe_b2, pe_w3, pe_b3, te_w1, te_b1, te_w2, te_b2, h, x);

    for (int l = 0; l < LL; ++l) {
        k_ln_aiaj<<<NB * NN / 4, 256, 0, stream>>>(h, ln_g + l * HH, ln_b + l * HH,
            ew1 + (size_t)l * 513 * HH, eb1 + l * HH, hn, Ai, AjB);
        k_edge<<<NB * NN, 512, 0, stream>>>(x, Ai, AjB,
            ew1 + ((size_t)l * 513 + 512) * HH, eb2 + l * HH,
            ew2P + (size_t)l * HH * HH, cw1P + (size_t)l * HH * HH,
            cb1 + l * HH, cw2 + l * HH, cb2 + l, magg, xdelta);
        k_node<<<NB * NN / 4, 256, 0, stream>>>(hn, magg,
            nw1 + (size_t)l * 2 * HH * HH, nb1 + l * HH,
            nw2 + (size_t)l * HH * HH, nb2 + l * HH, h, x, xdelta);
    }

    k_decoder<<<NB * NN / 4, 256, 0, stream>>>(h, dec_w1, dec_b1, dec_w2, dec_b2,
                                               dec_w3, dec_b3, (float*)d_out);
}

// Round 7
// 811.726 us; speedup vs baseline: 2.0960x; 1.1616x over previous
//
#include <hip/hip_runtime.h>
#include <math.h>

static constexpr int NB = 2, NN = 256, HH = 256, DD = 64, LL = 6;

typedef __attribute__((ext_vector_type(8))) short bf16x8;
typedef __attribute__((ext_vector_type(4))) float f32x4;
typedef __attribute__((ext_vector_type(4))) float float4v;
typedef __attribute__((ext_vector_type(4))) unsigned int u32x4;

// fast silu: v * rcp(1+exp(-v)). rcp is 1-ulp approx — fine for bf16 outputs.
// (plain v/(1+e) lowers to the ~12-inst IEEE div sequence without fast-math)
__device__ __forceinline__ float fsilu(float v) {
    return v * __builtin_amdgcn_rcpf(1.0f + __expf(-v));
}

__device__ __forceinline__ unsigned short f2bf(float f) {
    union { float f; unsigned int u; } x; x.f = f;
    unsigned int r = x.u + 0x7fffu + ((x.u >> 16) & 1u);
    return (unsigned short)(r >> 16);
}
__device__ __forceinline__ float bf2f(unsigned short u) {
    union { float f; unsigned int u; } x; x.u = ((unsigned int)u) << 16; return x.f;
}
__device__ __forceinline__ float bitsf(unsigned int u) {
    union { float f; unsigned int u; } x; x.u = u; return x.f;
}
// pack 2 f32 -> 2 bf16 in one instruction
__device__ __forceinline__ unsigned int cvtpk(float lo, float hi) {
    unsigned int w;
    asm("v_cvt_pk_bf16_f32 %0, %1, %2" : "=v"(w) : "v"(lo), "v"(hi));
    return w;
}

// ---------------------------------------------------------------- convert (fragment-packed)
// elem[(l*8192 + (ks*16 + wv*2 + ct)*64 + lane)*8 + e]
//   = bf16( W[l][ k = ks*32+(lane>>4)*8+e ][ col = wv*32+ct*16+(lane&15) ] )
__global__ void k_convert(const float* __restrict__ ew2, const float* __restrict__ cw1,
                          unsigned short* __restrict__ ew2P, unsigned short* __restrict__ cw1P) {
    int g = blockIdx.x * blockDim.x + threadIdx.x;
    if (g >= LL * 8192) return;
    int l = g >> 13;
    int r = g & 8191;
    int lane = r & 63;
    int fidx = r >> 6;
    int ks = fidx >> 4;
    int wv = (fidx >> 1) & 7;
    int ct = fidx & 1;
    int col = wv * 32 + ct * 16 + (lane & 15);
    int k0 = ks * 32 + (lane >> 4) * 8;
    #pragma unroll
    for (int e = 0; e < 8; ++e) {
        ew2P[(size_t)g * 8 + e] = f2bf(ew2[((size_t)l * HH + k0 + e) * HH + col]);
        cw1P[(size_t)g * 8 + e] = f2bf(cw1[((size_t)l * HH + k0 + e) * HH + col]);
    }
}

// ---------------------------------------------------------------- encoder (+time emb, x init)
__global__ __launch_bounds__(256) void k_encoder(
    const float* __restrict__ coords, const float* __restrict__ feats, const float* __restrict__ t,
    const float* __restrict__ pw1, const float* __restrict__ pb1,
    const float* __restrict__ pw2, const float* __restrict__ pb2,
    const float* __restrict__ pw3, const float* __restrict__ pb3,
    const float* __restrict__ tw1, const float* __restrict__ tb1,
    const float* __restrict__ tw2, const float* __restrict__ tb2,
    float* __restrict__ h, float* __restrict__ x) {
    __shared__ float spin[4][68];
    __shared__ float sha[4][HH];
    __shared__ float shb[4][HH];
    __shared__ float ste1[HH];
    int tid = threadIdx.x;
    int base = blockIdx.x * 4;
    int b = base / NN;

    for (int r = 0; r < 4; ++r) {
        int row = base + r;
        if (tid < 3) spin[r][tid] = coords[row * 3 + tid];
        if (tid < DD) spin[r][3 + tid] = feats[row * DD + tid];
    }
    float tv = t[b];
    ste1[tid] = fmaxf(tv * tw1[tid] + tb1[tid], 0.0f);
    if (tid < 12) {
        int r = tid / 3, c = tid % 3;
        x[(base + r) * 3 + c] = coords[(base + r) * 3 + c];
    }
    __syncthreads();

    float a0 = pb1[tid], a1 = a0, a2 = a0, a3 = a0;
    for (int c = 0; c < 67; ++c) {
        float w = pw1[c * HH + tid];
        a0 += spin[0][c] * w; a1 += spin[1][c] * w; a2 += spin[2][c] * w; a3 += spin[3][c] * w;
    }
    sha[0][tid] = fmaxf(a0, 0.f); sha[1][tid] = fmaxf(a1, 0.f);
    sha[2][tid] = fmaxf(a2, 0.f); sha[3][tid] = fmaxf(a3, 0.f);
    __syncthreads();
    a0 = pb2[tid]; a1 = a0; a2 = a0; a3 = a0;
    for (int c = 0; c < HH; ++c) {
        float w = pw2[c * HH + tid];
        a0 += sha[0][c] * w; a1 += sha[1][c] * w; a2 += sha[2][c] * w; a3 += sha[3][c] * w;
    }
    shb[0][tid] = fmaxf(a0, 0.f); shb[1][tid] = fmaxf(a1, 0.f);
    shb[2][tid] = fmaxf(a2, 0.f); shb[3][tid] = fmaxf(a3, 0.f);
    __syncthreads();
    a0 = pb3[tid]; a1 = a0; a2 = a0; a3 = a0;
    float te = tb2[tid];
    for (int c = 0; c < HH; ++c) {
        float w = pw3[c * HH + tid];
        a0 += shb[0][c] * w; a1 += shb[1][c] * w; a2 += shb[2][c] * w; a3 += shb[3][c] * w;
        te += ste1[c] * tw2[c * HH + tid];
    }
    h[(base + 0) * HH + tid] = fmaxf(a0, 0.f) + te;
    h[(base + 1) * HH + tid] = fmaxf(a1, 0.f) + te;
    h[(base + 2) * HH + tid] = fmaxf(a2, 0.f) + te;
    h[(base + 3) * HH + tid] = fmaxf(a3, 0.f) + te;
}

// ---------------------------------------------------------------- LayerNorm + Ai/Aj (layer 0 only)
__global__ __launch_bounds__(256) void k_ln_aiaj(
    const float* __restrict__ h, const float* __restrict__ g, const float* __restrict__ bta,
    const float* __restrict__ ew1l, const float* __restrict__ eb1l,
    float* __restrict__ hn, float* __restrict__ Ai, unsigned short* __restrict__ AjB) {
    __shared__ float shn[4][HH];
    int tid = threadIdx.x, w = tid >> 6, lane = tid & 63;
    int base = blockIdx.x * 4;
    int row = base + w;

    float v[4];
    #pragma unroll
    for (int q = 0; q < 4; ++q) v[q] = h[row * HH + lane + 64 * q];
    float s = v[0] + v[1] + v[2] + v[3];
    #pragma unroll
    for (int m = 1; m < 64; m <<= 1) s += __shfl_xor(s, m);
    float mu = s * (1.0f / HH);
    float var = 0.f;
    #pragma unroll
    for (int q = 0; q < 4; ++q) { v[q] -= mu; var += v[q] * v[q]; }
    #pragma unroll
    for (int m = 1; m < 64; m <<= 1) var += __shfl_xor(var, m);
    float rstd = rsqrtf(var * (1.0f / HH) + 1e-5f);
    #pragma unroll
    for (int q = 0; q < 4; ++q) {
        int k = lane + 64 * q;
        float hv = v[q] * rstd * g[k] + bta[k];
        shn[w][k] = hv;
        hn[row * HH + k] = hv;
    }
    __syncthreads();

    float ai0 = eb1l[tid], ai1 = ai0, ai2 = ai0, ai3 = ai0;
    float aj0 = 0.f, aj1 = 0.f, aj2 = 0.f, aj3 = 0.f;
    for (int c = 0; c < HH; ++c) {
        float wi = ew1l[c * HH + tid];
        float wj = ew1l[(HH + c) * HH + tid];
        float s0 = shn[0][c], s1 = shn[1][c], s2 = shn[2][c], s3 = shn[3][c];
        ai0 += s0 * wi; ai1 += s1 * wi; ai2 += s2 * wi; ai3 += s3 * wi;
        aj0 += s0 * wj; aj1 += s1 * wj; aj2 += s2 * wj; aj3 += s3 * wj;
    }
    Ai[(base + 0) * HH + tid] = ai0; AjB[(base + 0) * HH + tid] = f2bf(aj0);
    Ai[(base + 1) * HH + tid] = ai1; AjB[(base + 1) * HH + tid] = f2bf(aj1);
    Ai[(base + 2) * HH + tid] = ai2; AjB[(base + 2) * HH + tid] = f2bf(aj2);
    Ai[(base + 3) * HH + tid] = ai3; AjB[(base + 3) * HH + tid] = f2bf(aj3);
}

// ---------------------------------------------------------------- fused edge pipeline (MFMA)
// 512 threads = 8 waves, one block per (b,i). Wave owns 32 output cols.
// __launch_bounds__(512, 1): arg2 is min BLOCKS/CU (CUDA-style) on hipcc —
// (512,2) capped regalloc at 128 and spilled 110MB/dispatch (rounds 2-5).
__global__ __launch_bounds__(512, 1) void k_edge(
    const float* __restrict__ x, const float* __restrict__ Ai, const unsigned short* __restrict__ AjB,
    const float* __restrict__ wd, const float* __restrict__ eb2v,
    const unsigned short* __restrict__ ew2P, const unsigned short* __restrict__ cw1P,
    const float* __restrict__ cb1v, const float* __restrict__ cw2v, const float* __restrict__ cb2p,
    float* __restrict__ magg, float* __restrict__ xdelta) {
    __shared__ float srel[64][3];
    __shared__ float sd2[64];
    __shared__ float cwpart[8][64];
    __shared__ unsigned short s_tile[64 * 256];  // rows of 512B, XOR ((row&7)<<4)
    __shared__ unsigned short m_tile[64 * 256];

    int tid = threadIdx.x, wv = tid >> 6, lane = tid & 63;
    int g4 = lane >> 4, l15 = lane & 15;
    int colbase = wv * 32;
    int bi = blockIdx.x;
    int b = bi >> 8, i = bi & 255;
    int ni = b * NN + i;
    int bbase = b * NN;
    int bthr = ((wv << 7) + lane) << 3;  // packed-B elem offset; (ks,ct) adds (ks<<13)+(ct<<9)

    int k0p = (tid & 31) << 3;
    float aiv[8], wdv[8];
    {
        float4v a0 = *(const float4v*)(Ai + (size_t)ni * HH + k0p);
        float4v a1 = *(const float4v*)(Ai + (size_t)ni * HH + k0p + 4);
        float4v w0 = *(const float4v*)(wd + k0p);
        float4v w1 = *(const float4v*)(wd + k0p + 4);
        #pragma unroll
        for (int e = 0; e < 4; ++e) { aiv[e] = a0[e]; aiv[4 + e] = a1[e]; wdv[e] = w0[e]; wdv[4 + e] = w1[e]; }
    }
    float eb2r[2], cb1r[2], cw2r[2];
    #pragma unroll
    for (int ct = 0; ct < 2; ++ct) {
        int col = colbase + ct * 16 + l15;
        eb2r[ct] = eb2v[col]; cb1r[ct] = cb1v[col]; cw2r[ct] = cw2v[col];
    }
    float xi0 = x[ni * 3 + 0], xi1 = x[ni * 3 + 1], xi2 = x[ni * 3 + 2];
    float cb2 = cb2p[0];

    float mg[2] = {0.f, 0.f};
    float xd0 = 0.f, xd1 = 0.f, xd2 = 0.f;

    #pragma unroll 1
    for (int jc = 0; jc < 4; ++jc) {
        int j0 = jc * 64;
        __syncthreads();
        if (tid < 64) {
            int j = bbase + j0 + tid;
            float rx = xi0 - x[j * 3 + 0];
            float ry = xi1 - x[j * 3 + 1];
            float rz = xi2 - x[j * 3 + 2];
            srel[tid][0] = rx; srel[tid][1] = ry; srel[tid][2] = rz;
            sd2[tid] = rx * rx + ry * ry + rz * rz;
        }
        __syncthreads();

        // ---- phase 1: s tile = silu(Ai + Aj + d2*wd), 64x256 bf16
        #pragma unroll
        for (int it = 0; it < 4; ++it) {
            int row = it * 16 + (tid >> 5);
            float d2v = sd2[row];
            u32x4 ajw = *(const u32x4*)(AjB + ((size_t)(bbase + j0 + row) * HH + k0p));
            unsigned int uw0, uw1, uw2, uw3;
            {
                float alo = bitsf(ajw[0] << 16), ahi = bitsf(ajw[0] & 0xffff0000u);
                uw0 = cvtpk(fsilu(aiv[0] + alo + d2v * wdv[0]), fsilu(aiv[1] + ahi + d2v * wdv[1]));
            }
            {
                float alo = bitsf(ajw[1] << 16), ahi = bitsf(ajw[1] & 0xffff0000u);
                uw1 = cvtpk(fsilu(aiv[2] + alo + d2v * wdv[2]), fsilu(aiv[3] + ahi + d2v * wdv[3]));
            }
            {
                float alo = bitsf(ajw[2] << 16), ahi = bitsf(ajw[2] & 0xffff0000u);
                uw2 = cvtpk(fsilu(aiv[4] + alo + d2v * wdv[4]), fsilu(aiv[5] + ahi + d2v * wdv[5]));
            }
            {
                float alo = bitsf(ajw[3] << 16), ahi = bitsf(ajw[3] & 0xffff0000u);
                uw3 = cvtpk(fsilu(aiv[6] + alo + d2v * wdv[6]), fsilu(aiv[7] + ahi + d2v * wdv[7]));
            }
            u32x4 sv = {uw0, uw1, uw2, uw3};
            unsigned off = (unsigned)(row * 512 + k0p * 2) ^ (unsigned)((row & 7) << 4);
            *reinterpret_cast<u32x4*>(reinterpret_cast<char*>(s_tile) + off) = sv;
        }
        __syncthreads();

        // ---- phase 2: m = silu(s @ ew2 + eb2), two 32-row half-passes
        #pragma unroll 1
        for (int rh = 0; rh < 2; ++rh) {
            f32x4 acc[2][2];
            acc[0][0] = (f32x4){0.f,0.f,0.f,0.f}; acc[0][1] = (f32x4){0.f,0.f,0.f,0.f};
            acc[1][0] = (f32x4){0.f,0.f,0.f,0.f}; acc[1][1] = (f32x4){0.f,0.f,0.f,0.f};
            bf16x8 bc0 = *(const bf16x8*)(ew2P + bthr);
            bf16x8 bc1 = *(const bf16x8*)(ew2P + (1 << 9) + bthr);
            #pragma unroll
            for (int ks = 0; ks < 8; ++ks) {
                bf16x8 bn0, bn1;
                if (ks < 7) {
                    bn0 = *(const bf16x8*)(ew2P + ((ks + 1) << 13) + bthr);
                    bn1 = *(const bf16x8*)(ew2P + ((ks + 1) << 13) + (1 << 9) + bthr);
                }
                int ak = ks * 32 + g4 * 8;
                int row0 = rh * 32 + l15;
                int row1 = row0 + 16;
                unsigned off0 = (unsigned)(row0 * 512 + ak * 2) ^ (unsigned)((row0 & 7) << 4);
                unsigned off1 = (unsigned)(row1 * 512 + ak * 2) ^ (unsigned)((row1 & 7) << 4);
                bf16x8 a0 = *reinterpret_cast<const bf16x8*>(reinterpret_cast<const char*>(s_tile) + off0);
                bf16x8 a1 = *reinterpret_cast<const bf16x8*>(reinterpret_cast<const char*>(s_tile) + off1);
                acc[0][0] = __builtin_amdgcn_mfma_f32_16x16x32_bf16(a0, bc0, acc[0][0], 0, 0, 0);
                acc[0][1] = __builtin_amdgcn_mfma_f32_16x16x32_bf16(a0, bc1, acc[0][1], 0, 0, 0);
                acc[1][0] = __builtin_amdgcn_mfma_f32_16x16x32_bf16(a1, bc0, acc[1][0], 0, 0, 0);
                acc[1][1] = __builtin_amdgcn_mfma_f32_16x16x32_bf16(a1, bc1, acc[1][1], 0, 0, 0);
                if (ks < 7) { bc0 = bn0; bc1 = bn1; }
            }
            // epilogue: silu + pack (pair across ct: same row, cols 16 apart)
            #pragma unroll
            for (int rt = 0; rt < 2; ++rt) {
                #pragma unroll
                for (int r = 0; r < 4; ++r) {
                    int row = rh * 32 + rt * 16 + g4 * 4 + r;
                    float v0 = fsilu(acc[rt][0][r] + eb2r[0]);
                    float v1 = fsilu(acc[rt][1][r] + eb2r[1]);
                    mg[0] += v0; mg[1] += v1;
                    unsigned int w = cvtpk(v0, v1);
                    unsigned swz = (unsigned)((row & 7) << 4);
                    unsigned off0 = (unsigned)(row * 512 + (colbase + l15) * 2) ^ swz;
                    unsigned off1 = (unsigned)(row * 512 + (colbase + 16 + l15) * 2) ^ swz;
                    *reinterpret_cast<unsigned short*>(reinterpret_cast<char*>(m_tile) + off0) = (unsigned short)w;
                    *reinterpret_cast<unsigned short*>(reinterpret_cast<char*>(m_tile) + off1) = (unsigned short)(w >> 16);
                }
            }
        }
        __syncthreads();

        // ---- phase 3: c = silu(m @ cw1 + cb1); cw-row-dot with cw2 (two half-passes)
        #pragma unroll 1
        for (int rh = 0; rh < 2; ++rh) {
            f32x4 acc[2][2];
            acc[0][0] = (f32x4){0.f,0.f,0.f,0.f}; acc[0][1] = (f32x4){0.f,0.f,0.f,0.f};
            acc[1][0] = (f32x4){0.f,0.f,0.f,0.f}; acc[1][1] = (f32x4){0.f,0.f,0.f,0.f};
            bf16x8 bc0 = *(const bf16x8*)(cw1P + bthr);
            bf16x8 bc1 = *(const bf16x8*)(cw1P + (1 << 9) + bthr);
            #pragma unroll
            for (int ks = 0; ks < 8; ++ks) {
                bf16x8 bn0, bn1;
                if (ks < 7) {
                    bn0 = *(const bf16x8*)(cw1P + ((ks + 1) << 13) + bthr);
                    bn1 = *(const bf16x8*)(cw1P + ((ks + 1) << 13) + (1 << 9) + bthr);
                }
                int ak = ks * 32 + g4 * 8;
                int row0 = rh * 32 + l15;
                int row1 = row0 + 16;
                unsigned off0 = (unsigned)(row0 * 512 + ak * 2) ^ (unsigned)((row0 & 7) << 4);
                unsigned off1 = (unsigned)(row1 * 512 + ak * 2) ^ (unsigned)((row1 & 7) << 4);
                bf16x8 a0 = *reinterpret_cast<const bf16x8*>(reinterpret_cast<const char*>(m_tile) + off0);
                bf16x8 a1 = *reinterpret_cast<const bf16x8*>(reinterpret_cast<const char*>(m_tile) + off1);
                acc[0][0] = __builtin_amdgcn_mfma_f32_16x16x32_bf16(a0, bc0, acc[0][0], 0, 0, 0);
                acc[0][1] = __builtin_amdgcn_mfma_f32_16x16x32_bf16(a0, bc1, acc[0][1], 0, 0, 0);
                acc[1][0] = __builtin_amdgcn_mfma_f32_16x16x32_bf16(a1, bc0, acc[1][0], 0, 0, 0);
                acc[1][1] = __builtin_amdgcn_mfma_f32_16x16x32_bf16(a1, bc1, acc[1][1], 0, 0, 0);
                if (ks < 7) { bc0 = bn0; bc1 = bn1; }
            }
            float rs[8];
            #pragma unroll
            for (int q = 0; q < 8; ++q) rs[q] = 0.f;
            #pragma unroll
            for (int ct = 0; ct < 2; ++ct) {
                #pragma unroll
                for (int rt = 0; rt < 2; ++rt)
                    #pragma unroll
                    for (int r = 0; r < 4; ++r)
                        rs[rt * 4 + r] += fsilu(acc[rt][ct][r] + cb1r[ct]) * cw2r[ct];
            }
            #pragma unroll
            for (int m = 1; m <= 8; m <<= 1)
                #pragma unroll
                for (int q = 0; q < 8; ++q) rs[q] += __shfl_xor(rs[q], m);
            if (l15 == 0) {
                #pragma unroll
                for (int rt = 0; rt < 2; ++rt)
                    #pragma unroll
                    for (int r = 0; r < 4; ++r)
                        cwpart[wv][rh * 32 + rt * 16 + g4 * 4 + r] = rs[rt * 4 + r];
            }
        }
        __syncthreads();
        if (tid < 64) {
            float cwv = cb2;
            #pragma unroll
            for (int w = 0; w < 8; ++w) cwv += cwpart[w][tid];
            float p0 = srel[tid][0] * cwv;
            float p1 = srel[tid][1] * cwv;
            float p2 = srel[tid][2] * cwv;
            #pragma unroll
            for (int m = 1; m < 64; m <<= 1) {
                p0 += __shfl_xor(p0, m); p1 += __shfl_xor(p1, m); p2 += __shfl_xor(p2, m);
            }
            xd0 += p0; xd1 += p1; xd2 += p2;
        }
    }

    #pragma unroll
    for (int ct = 0; ct < 2; ++ct) {
        mg[ct] += __shfl_xor(mg[ct], 16);
        mg[ct] += __shfl_xor(mg[ct], 32);
    }
    if (lane < 16) {
        #pragma unroll
        for (int ct = 0; ct < 2; ++ct)
            magg[(size_t)ni * HH + colbase + ct * 16 + lane] = mg[ct];
    }
    if (tid == 0) {
        xdelta[ni * 3 + 0] = xd0 * (1.0f / NN);
        xdelta[ni * 3 + 1] = xd1 * (1.0f / NN);
        xdelta[ni * 3 + 2] = xd2 * (1.0f / NN);
    }
}

// ---------------------------------------------------------------- fused node update + next-layer LN/Ai/Aj
// Same 4 rows as the old k_node + k_ln_aiaj -> fuse: update h (+x), then (if
// has_ln) LayerNorm the fresh h from LDS and compute next layer's Ai/Aj.
__global__ __launch_bounds__(256) void k_node_ln(
    const float* __restrict__ hn, const float* __restrict__ magg,
    const float* __restrict__ nw1l, const float* __restrict__ nb1l,
    const float* __restrict__ nw2l, const float* __restrict__ nb2l,
    float* __restrict__ h, float* __restrict__ x, const float* __restrict__ xdelta,
    const float* __restrict__ g, const float* __restrict__ bta,
    const float* __restrict__ ew1l, const float* __restrict__ eb1l,
    float* __restrict__ hnout, float* __restrict__ Ai, unsigned short* __restrict__ AjB,
    int has_ln) {
    __shared__ float s2[4][2 * HH];
    __shared__ float su[4][HH];
    __shared__ float sh[4][HH];
    __shared__ float shn[4][HH];
    int tid = threadIdx.x;
    int base = blockIdx.x * 4;
    for (int r = 0; r < 4; ++r) {
        s2[r][tid] = hn[(base + r) * HH + tid];
        s2[r][HH + tid] = magg[(base + r) * HH + tid];
    }
    if (tid < 12) {
        int r = tid / 3, c = tid % 3;
        x[(base + r) * 3 + c] += xdelta[(base + r) * 3 + c];
    }
    __syncthreads();
    float a0 = nb1l[tid], a1 = a0, a2 = a0, a3 = a0;
    for (int c = 0; c < 2 * HH; ++c) {
        float w = nw1l[c * HH + tid];
        a0 += s2[0][c] * w; a1 += s2[1][c] * w; a2 += s2[2][c] * w; a3 += s2[3][c] * w;
    }
    su[0][tid] = fsilu(a0); su[1][tid] = fsilu(a1); su[2][tid] = fsilu(a2); su[3][tid] = fsilu(a3);
    __syncthreads();
    float d0 = nb2l[tid], d1 = d0, d2 = d0, d3 = d0;
    for (int c = 0; c < HH; ++c) {
        float w = nw2l[c * HH + tid];
        d0 += su[0][c] * w; d1 += su[1][c] * w; d2 += su[2][c] * w; d3 += su[3][c] * w;
    }
    float h0 = h[(base + 0) * HH + tid] + d0;
    float h1 = h[(base + 1) * HH + tid] + d1;
    float h2 = h[(base + 2) * HH + tid] + d2;
    float h3 = h[(base + 3) * HH + tid] + d3;
    h[(base + 0) * HH + tid] = h0;
    h[(base + 1) * HH + tid] = h1;
    h[(base + 2) * HH + tid] = h2;
    h[(base + 3) * HH + tid] = h3;
    if (!has_ln) return;
    sh[0][tid] = h0; sh[1][tid] = h1; sh[2][tid] = h2; sh[3][tid] = h3;
    __syncthreads();

    // LayerNorm (one wave per row) reading fresh h from LDS
    {
        int w = tid >> 6, lane = tid & 63;
        int row = base + w;
        float v[4];
        #pragma unroll
        for (int q = 0; q < 4; ++q) v[q] = sh[w][lane + 64 * q];
        float s = v[0] + v[1] + v[2] + v[3];
        #pragma unroll
        for (int m = 1; m < 64; m <<= 1) s += __shfl_xor(s, m);
        float mu = s * (1.0f / HH);
        float var = 0.f;
        #pragma unroll
        for (int q = 0; q < 4; ++q) { v[q] -= mu; var += v[q] * v[q]; }
        #pragma unroll
        for (int m = 1; m < 64; m <<= 1) var += __shfl_xor(var, m);
        float rstd = rsqrtf(var * (1.0f / HH) + 1e-5f);
        #pragma unroll
        for (int q = 0; q < 4; ++q) {
            int k = lane + 64 * q;
            float hv = v[q] * rstd * g[k] + bta[k];
            shn[w][k] = hv;
            hnout[row * HH + k] = hv;
        }
    }
    __syncthreads();

    float ai0 = eb1l[tid], ai1 = ai0, ai2 = ai0, ai3 = ai0;
    float aj0 = 0.f, aj1 = 0.f, aj2 = 0.f, aj3 = 0.f;
    for (int c = 0; c < HH; ++c) {
        float wi = ew1l[c * HH + tid];
        float wj = ew1l[(HH + c) * HH + tid];
        float s0 = shn[0][c], s1 = shn[1][c], s2 = shn[2][c], s3 = shn[3][c];
        ai0 += s0 * wi; ai1 += s1 * wi; ai2 += s2 * wi; ai3 += s3 * wi;
        aj0 += s0 * wj; aj1 += s1 * wj; aj2 += s2 * wj; aj3 += s3 * wj;
    }
    Ai[(base + 0) * HH + tid] = ai0; AjB[(base + 0) * HH + tid] = f2bf(aj0);
    Ai[(base + 1) * HH + tid] = ai1; AjB[(base + 1) * HH + tid] = f2bf(aj1);
    Ai[(base + 2) * HH + tid] = ai2; AjB[(base + 2) * HH + tid] = f2bf(aj2);
    Ai[(base + 3) * HH + tid] = ai3; AjB[(base + 3) * HH + tid] = f2bf(aj3);
}

// ---------------------------------------------------------------- decoder
__global__ __launch_bounds__(256) void k_decoder(
    const float* __restrict__ h,
    const float* __restrict__ dw1, const float* __restrict__ db1,
    const float* __restrict__ dw2, const float* __restrict__ db2,
    const float* __restrict__ dw3, const float* __restrict__ db3,
    float* __restrict__ out) {
    __shared__ float sh[4][HH];
    __shared__ float so1[4][HH];
    __shared__ float so2[4][HH];
    int tid = threadIdx.x;
    int base = blockIdx.x * 4;
    for (int r = 0; r < 4; ++r) sh[r][tid] = h[(base + r) * HH + tid];
    __syncthreads();
    float a0 = db1[tid], a1 = a0, a2 = a0, a3 = a0;
    for (int c = 0; c < HH; ++c) {
        float w = dw1[c * HH + tid];
        a0 += sh[0][c] * w; a1 += sh[1][c] * w; a2 += sh[2][c] * w; a3 += sh[3][c] * w;
    }
    so1[0][tid] = fmaxf(a0, 0.f); so1[1][tid] = fmaxf(a1, 0.f);
    so1[2][tid] = fmaxf(a2, 0.f); so1[3][tid] = fmaxf(a3, 0.f);
    __syncthreads();
    a0 = db2[tid]; a1 = a0; a2 = a0; a3 = a0;
    for (int c = 0; c < HH; ++c) {
        float w = dw2[c * HH + tid];
        a0 += so1[0][c] * w; a1 += so1[1][c] * w; a2 += so1[2][c] * w; a3 += so1[3][c] * w;
    }
    so2[0][tid] = fmaxf(a0, 0.f) + sh[0][tid];
    so2[1][tid] = fmaxf(a1, 0.f) + sh[1][tid];
    so2[2][tid] = fmaxf(a2, 0.f) + sh[2][tid];
    so2[3][tid] = fmaxf(a3, 0.f) + sh[3][tid];
    __syncthreads();
    if (tid < 12) {
        int r = tid / 3, c = tid % 3;
        float acc = db3[c];
        for (int k = 0; k < HH; ++k) acc += so2[r][k] * dw3[k * 3 + c];
        out[(base + r) * 3 + c] = acc;
    }
}

// ---------------------------------------------------------------- launch
extern "C" void kernel_launch(void* const* d_in, const int* in_sizes, int n_in,
                              void* d_out, int out_size, void* d_ws, size_t ws_size,
                              hipStream_t stream) {
    const float* coords = (const float*)d_in[0];
    const float* feats  = (const float*)d_in[1];
    const float* t      = (const float*)d_in[2];
    const float* pe_w1  = (const float*)d_in[3];  const float* pe_b1 = (const float*)d_in[4];
    const float* pe_w2  = (const float*)d_in[5];  const float* pe_b2 = (const float*)d_in[6];
    const float* pe_w3  = (const float*)d_in[7];  const float* pe_b3 = (const float*)d_in[8];
    const float* te_w1  = (const float*)d_in[9];  const float* te_b1 = (const float*)d_in[10];
    const float* te_w2  = (const float*)d_in[11]; const float* te_b2 = (const float*)d_in[12];
    const float* ln_g   = (const float*)d_in[13]; const float* ln_b  = (const float*)d_in[14];
    const float* ew1    = (const float*)d_in[15]; const float* eb1   = (const float*)d_in[16];
    const float* ew2    = (const float*)d_in[17]; const float* eb2   = (const float*)d_in[18];
    const float* cw1    = (const float*)d_in[19]; const float* cb1   = (const float*)d_in[20];
    const float* cw2    = (const float*)d_in[21]; const float* cb2   = (const float*)d_in[22];
    const float* nw1    = (const float*)d_in[23]; const float* nb1   = (const float*)d_in[24];
    const float* nw2    = (const float*)d_in[25]; const float* nb2   = (const float*)d_in[26];
    const float* dec_w1 = (const float*)d_in[27]; const float* dec_b1 = (const float*)d_in[28];
    const float* dec_w2 = (const float*)d_in[29]; const float* dec_b2 = (const float*)d_in[30];
    const float* dec_w3 = (const float*)d_in[31]; const float* dec_b3 = (const float*)d_in[32];

    float* ws = (float*)d_ws;
    const int RN = NB * NN * HH;  // 131072
    float* h      = ws;
    float* hn     = ws + RN;
    float* Ai     = ws + 2 * RN;
    float* magg   = ws + 3 * RN;
    float* x      = ws + 4 * RN;
    float* xdelta = ws + 4 * RN + 2048;
    unsigned short* AjB  = (unsigned short*)(ws + 4 * RN + 4096);
    unsigned short* ew2P = AjB + RN;
    unsigned short* cw1P = ew2P + LL * HH * HH;

    k_convert<<<(LL * 8192 + 511) / 512, 512, 0, stream>>>(ew2, cw1, ew2P, cw1P);
    k_encoder<<<NB * NN / 4, 256, 0, stream>>>(coords, feats, t,
        pe_w1, pe_b1, pe_w2, pe_b2, pe_w3, pe_b3, te_w1, te_b1, te_w2, te_b2, h, x);
    k_ln_aiaj<<<NB * NN / 4, 256, 0, stream>>>(h, ln_g, ln_b, ew1, eb1, hn, Ai, AjB);

    for (int l = 0; l < LL; ++l) {
        k_edge<<<NB * NN, 512, 0, stream>>>(x, Ai, AjB,
            ew1 + ((size_t)l * 513 + 512) * HH, eb2 + l * HH,
            ew2P + (size_t)l * HH * HH, cw1P + (size_t)l * HH * HH,
            cb1 + l * HH, cw2 + l * HH, cb2 + l, magg, xdelta);
        int ln = (l + 1 < LL) ? (l + 1) : LL - 1;  // params unused when has_ln=0
        k_node_ln<<<NB * NN / 4, 256, 0, stream>>>(hn, magg,
            nw1 + (size_t)l * 2 * HH * HH, nb1 + l * HH,
            nw2 + (size_t)l * HH * HH, nb2 + l * HH, h, x, xdelta,
            ln_g + ln * HH, ln_b + ln * HH,
            ew1 + (size_t)ln * 513 * HH, eb1 + ln * HH,
            hn, Ai, AjB, (l + 1 < LL) ? 1 : 0);
    }

    k_decoder<<<NB * NN / 4, 256, 0, stream>>>(h, dec_w1, dec_b1, dec_w2, dec_b2,
                                               dec_w3, dec_b3, (float*)d_out);
}